// Round 16
// baseline (1702.465 us; speedup 1.0000x reference)
//
#include <hip/hip_runtime.h>
#include <hip/hip_bf16.h>

#define DEV static __device__ __forceinline__

typedef short v8s __attribute__((ext_vector_type(8)));
typedef float v4f __attribute__((ext_vector_type(4)));
typedef unsigned short v4u __attribute__((ext_vector_type(4)));

constexpr int N_ = 8;
constexpr float EPS_ = 1e-5f;
constexpr float INV_CNT = 1.f / 524288.f;   // 1/(8*256*256)
constexpr int CHB = 12800;                  // ushorts per staging buffer (25600 B)

// c2 granule layout v1 (block-private aliasing with d_out, full-row haar blocks):
//   element (n, hr, wc, ch), r=hr&1, row=hr>>1  ->  ushort offset
//   r*16777216 + n*2097152 + (wc>>2)*32768 + row*256 + (wc&3)*64 + ch
// haar block (n,row) reads exactly the granules its own out_low (r=0) /
// convh (r=1) stores later clobber -> same-block ordering only.

// device-global scratch
__device__ __align__(16) unsigned short g_wT1[9*128*64];   // [tap][oc][ic] bf16
__device__ __align__(16) unsigned short g_wT2[9*64*128];
__device__ __align__(16) unsigned short g_whT[64*192];     // [oc][k] bf16
__device__ __align__(16) float g_stats[512];               // s1[0:256) s2[256:384) sH[384:512)
__device__ __align__(16) unsigned short g_zero[64];

DEV float bfbits2f(unsigned short u) { return __uint_as_float(((unsigned)u) << 16); }
DEV unsigned short f2bfbits(float f) {
    __hip_bfloat16 h = __float2bfloat16(f);
    unsigned short b;
    __builtin_memcpy(&b, &h, 2);
    return b;
}

DEV float mishf(float v) {
    // mish(v) = v * t(t+2)/(t(t+2)+2), t = e^v
    float t = __expf(fminf(v, 30.f));
    float num = fmaf(t, t, 2.f * t);
    return v * num * __builtin_amdgcn_rcpf(num + 2.f);
}

DEV void gll16(const unsigned short* g, unsigned short* l) {
    __builtin_amdgcn_global_load_lds(
        (const __attribute__((address_space(1))) unsigned int*)g,
        (__attribute__((address_space(3))) unsigned int*)l,
        16, 0, 0);
}

// ---------------------------------------------------------------------------
// prep: weight reorders (bf16) + zero stats + zero page
// ---------------------------------------------------------------------------
__global__ __launch_bounds__(256) void prep(const float* __restrict__ w1,
                                            const float* __restrict__ w2,
                                            const float* __restrict__ wh)
{
    int idx = blockIdx.x * 256 + threadIdx.x;
    if (idx < 512) g_stats[idx] = 0.f;
    if (idx < 64) g_zero[idx] = 0;
    if (idx < 12288) g_whT[idx] = f2bfbits(wh[idx]);       // [oc][192] == OIHW flat
    if (idx < 73728) {
        int tap = idx / 8192, rem = idx & 8191;
        {   int oc = rem >> 6, ic = rem & 63;
            g_wT1[idx] = f2bfbits(w1[(oc * 64 + ic) * 9 + tap]); }
        {   int oc = rem >> 7, ic = rem & 127;
            g_wT2[idx] = f2bfbits(w2[(oc * 128 + ic) * 9 + tap]); }
    }
}

// ---------------------------------------------------------------------------
// transpose x: NCHW f32 -> NHWC bf16
// ---------------------------------------------------------------------------
__global__ __launch_bounds__(256) void transpose_x(const float* __restrict__ x,
                                                   unsigned short* __restrict__ xh)
{
    __shared__ float t[64][65];
    const int tid = threadIdx.x;
    const int bid = blockIdx.x;
    const int n = bid >> 10, pb = bid & 1023;
    const size_t pix0 = (size_t)pb * 64;
    const float* xb = x + ((size_t)n << 22) + pix0;
#pragma unroll
    for (int cb = 0; cb < 4; ++cb) {
        int c = (tid >> 4) + cb * 16;
        int p = (tid & 15) * 4;
        float4 v = *(const float4*)(xb + ((size_t)c << 16) + p);
        t[c][p] = v.x; t[c][p+1] = v.y; t[c][p+2] = v.z; t[c][p+3] = v.w;
    }
    __syncthreads();
    unsigned short* ob = xh + (((size_t)n << 16) + pix0) * 64;
#pragma unroll
    for (int pb2 = 0; pb2 < 2; ++pb2) {
        int p = (tid >> 3) + pb2 * 32;
        int c0 = (tid & 7) * 8;
        v8s r;
#pragma unroll
        for (int i = 0; i < 8; ++i) r[i] = (short)f2bfbits(t[c0 + i][p]);
        *(v8s*)(ob + (size_t)p * 64 + c0) = r;
    }
}

// ---------------------------------------------------------------------------
// conv1: MFMA 3x3, pad=1, NHWC bf16, 64ic -> 128oc. 64-px tiles, all 128 oc.
// 3-deep counted-vmcnt pipeline (R14, best measured).
// Block 512 thr = 8 waves = 4 ocw x 2 pxg; wave 32 oc x 32 px.
// ---------------------------------------------------------------------------
__global__ __launch_bounds__(512, 2) void conv1MFMA(const unsigned short* __restrict__ in,
                                                    unsigned short* __restrict__ outp,
                                                    const int nTiles)
{
    __shared__ __align__(16) unsigned short Xs[3 * CHB + 512];   // 77824 B
    const int tid  = threadIdx.x;
    const int lane = tid & 63;
    const int wv   = tid >> 6;
    const int pg   = (int)blockIdx.x;
    const int NPG  = (int)gridDim.x;

    const int ocw = wv >> 1;              // 0..3 (32-oc group)
    const int wp  = (wv & 1) * 32;        // wave pixel offset
    const int l15 = lane & 15, kg = lane >> 4;

    v8s av[9][2][2];
    {
        const unsigned short* wb =
            g_wT1 + ((size_t)(ocw * 32 + l15)) * 64 + kg * 8;
#pragma unroll
        for (int tap = 0; tap < 9; ++tap)
#pragma unroll
            for (int ics = 0; ics < 2; ++ics)
#pragma unroll
                for (int sub = 0; sub < 2; ++sub)
                    av[tap][ics][sub] =
                        *(const v8s*)(wb + ((size_t)tap * 128 + sub * 16) * 64 + ics * 32);
    }

    auto stage = [&](int s) {
        const int pt   = pg + NPG * s;
        const int n    = pt >> 10;
        const int hrow = (pt >> 2) & 255;
        const int w0   = (pt & 3) * 64;
        unsigned short* buf = Xs + (s % 3) * CHB;
#pragma unroll
        for (int it = 0; it < 4; ++it) {
            const int cb = it * 512 + wv * 64;               // wave-uniform
            unsigned short* dst = (cb >= 1600) ? (Xs + 3 * CHB)
                                               : (buf + (size_t)cb * 8);
            const int chunk = cb + lane;
            int r   = chunk / 528;
            int rem = chunk - r * 528;
            int lc  = rem >> 3, k = rem & 7;
            int gr  = hrow - 1 + r;
            int gc  = w0 - 1 + lc;
            const unsigned short* src;
            if ((chunk < 1584) & ((unsigned)gr < 256u) & ((unsigned)gc < 256u))
                src = in + ((((size_t)n << 16) + ((size_t)gr << 8) + gc) * 64)
                         + ((k ^ (lc & 7)) << 3);
            else
                src = g_zero;
            gll16(src, dst);                                 // always issued: 4/wave
        }
    };

    stage(0);
    stage(1);
    asm volatile("s_waitcnt vmcnt(4)" ::: "memory");   // drain stage(0) (+av)
    __builtin_amdgcn_s_barrier();
    __builtin_amdgcn_sched_barrier(0);

    for (int s = 0; s < nTiles; ++s) {
        if (s + 2 < nTiles) stage(s + 2);                // fly across 2 barriers

        const unsigned short* cur = Xs + (s % 3) * CHB;
        const int pt   = pg + NPG * s;
        const int n    = pt >> 10;
        const int hrow = (pt >> 2) & 255;
        const int w0   = (pt & 3) * 64;
        const size_t pixbase = ((size_t)n << 16) + ((size_t)hrow << 8) + w0;

        v4f acc[2][2];
        {
            v4f z = {0.f, 0.f, 0.f, 0.f};
            acc[0][0] = z; acc[0][1] = z; acc[1][0] = z; acc[1][1] = z;
        }
#pragma unroll
        for (int tap = 0; tap < 9; ++tap) {
            const int dyy = tap / 3, dxx = tap % 3;
            const int lc0 = wp + l15 + dxx;
#pragma unroll
            for (int ics = 0; ics < 2; ++ics) {
                const int off0 = ((dyy * 66 + lc0) * 8 + ((ics * 4 + kg) ^ (lc0 & 7))) * 8;
                v8s b0 = *(const v8s*)(cur + off0);
                v8s b1 = *(const v8s*)(cur + off0 + 16 * 64);   // lc0+16: same (lc&7)
                acc[0][0] = __builtin_amdgcn_mfma_f32_16x16x32_bf16(av[tap][ics][0], b0, acc[0][0], 0, 0, 0);
                acc[1][0] = __builtin_amdgcn_mfma_f32_16x16x32_bf16(av[tap][ics][1], b0, acc[1][0], 0, 0, 0);
                acc[0][1] = __builtin_amdgcn_mfma_f32_16x16x32_bf16(av[tap][ics][0], b1, acc[0][1], 0, 0, 0);
                acc[1][1] = __builtin_amdgcn_mfma_f32_16x16x32_bf16(av[tap][ics][1], b1, acc[1][1], 0, 0, 0);
            }
        }

        if (s + 2 < nTiles) asm volatile("s_waitcnt vmcnt(4)" ::: "memory");
        else                asm volatile("s_waitcnt vmcnt(0)" ::: "memory");

#pragma unroll
        for (int sub = 0; sub < 2; ++sub)
#pragma unroll
            for (int ps = 0; ps < 2; ++ps) {
                const int px  = wp + ps * 16 + l15;
                const int ocb = ocw * 32 + sub * 16 + kg * 4;
                size_t gaddr = (pixbase + px) * 128 + ocb;
                v4f a = acc[sub][ps];
                v4u pk;
#pragma unroll
                for (int r = 0; r < 4; ++r) pk[r] = f2bfbits(a[r]);
                *(v4u*)(outp + gaddr) = pk;
            }

        __builtin_amdgcn_s_barrier();
        __builtin_amdgcn_sched_barrier(0);
    }
}

// ---------------------------------------------------------------------------
// conv2: single-pass MFMA 3x3, 128ic -> 64oc, granule-v1 output.
// 3-DEEP pipeline over (tile, ic-half) steps s = 2t+h, NS = nTiles*2; body
// unrolled into two STATIC halves (av indices compile-time, rule #20); buffer
// selection is runtime pointer arithmetic (legal). Counted vmcnt as conv1.
// Block 512 thr = 8 waves = 4 ocq x 2 pxg; wave 16 oc x 32 px.
// ---------------------------------------------------------------------------
__global__ __launch_bounds__(512, 2) void conv2MFMA(const unsigned short* __restrict__ in,
                                                    unsigned short* __restrict__ outp,
                                                    const int nTiles)
{
    __shared__ __align__(16) unsigned short Xs[3 * CHB + 512];   // 77824 B
    const int tid  = threadIdx.x;
    const int lane = tid & 63;
    const int wv   = tid >> 6;
    const int pg   = (int)blockIdx.x;
    const int NPG  = (int)gridDim.x;

    const int ocq = wv >> 1;              // 0..3 (16-oc group)
    const int wp  = (wv & 1) * 32;
    const int l15 = lane & 15, kg = lane >> 4;

    v8s av[9][4];
    {
        const unsigned short* wb =
            g_wT2 + ((size_t)(ocq * 16 + l15)) * 128 + kg * 8;
#pragma unroll
        for (int tap = 0; tap < 9; ++tap)
#pragma unroll
            for (int ics = 0; ics < 4; ++ics)
                av[tap][ics] = *(const v8s*)(wb + (size_t)tap * 64 * 128 + ics * 32);
    }

    auto stageH = [&](int s) {            // step s: tile s>>1, ic-half s&1
        const int tt    = s >> 1;
        const int icoff = (s & 1) * 64;
        const int pt   = pg + NPG * tt;
        const int n    = pt >> 10;
        const int hrow = (pt >> 2) & 255;
        const int w0   = (pt & 3) * 64;
#pragma unroll
        for (int it = 0; it < 4; ++it) {
            const int cb = it * 512 + wv * 64;
            unsigned short* buf = Xs + (s % 3) * CHB;
            unsigned short* dst = (cb >= 1600) ? (Xs + 3 * CHB)
                                               : (buf + (size_t)cb * 8);
            const int chunk = cb + lane;
            int r   = chunk / 528;
            int rem = chunk - r * 528;
            int lc  = rem >> 3, k = rem & 7;
            int gr  = hrow - 1 + r;
            int gc  = w0 - 1 + lc;
            const unsigned short* src;
            if ((chunk < 1584) & ((unsigned)gr < 256u) & ((unsigned)gc < 256u))
                src = in + ((((size_t)n << 16) + ((size_t)gr << 8) + gc) * 128)
                         + icoff + ((k ^ (lc & 7)) << 3);
            else
                src = g_zero;
            gll16(src, dst);
        }
    };

    const int NS = nTiles * 2;
    stageH(0);
    stageH(1);
    asm volatile("s_waitcnt vmcnt(4)" ::: "memory");
    __builtin_amdgcn_s_barrier();
    __builtin_amdgcn_sched_barrier(0);

    for (int t = 0; t < nTiles; ++t) {
        const int s0 = 2 * t;
        v4f acc[2];
        {
            v4f z = {0.f, 0.f, 0.f, 0.f};
            acc[0] = z; acc[1] = z;
        }

        // ---- even step s0: ic 0..63 from buf[s0%3]
        if (s0 + 2 < NS) stageH(s0 + 2);
        {
            const unsigned short* cur = Xs + (s0 % 3) * CHB;
#pragma unroll
            for (int tap = 0; tap < 9; ++tap) {
                const int dyy = tap / 3, dxx = tap % 3;
                const int lc0 = wp + l15 + dxx;
#pragma unroll
                for (int i2 = 0; i2 < 2; ++i2) {
                    const int off0 = ((dyy * 66 + lc0) * 8 + ((i2 * 4 + kg) ^ (lc0 & 7))) * 8;
                    v8s b0 = *(const v8s*)(cur + off0);
                    v8s b1 = *(const v8s*)(cur + off0 + 16 * 64);
                    acc[0] = __builtin_amdgcn_mfma_f32_16x16x32_bf16(av[tap][i2], b0, acc[0], 0, 0, 0);
                    acc[1] = __builtin_amdgcn_mfma_f32_16x16x32_bf16(av[tap][i2], b1, acc[1], 0, 0, 0);
                }
            }
        }
        if (s0 + 2 < NS) asm volatile("s_waitcnt vmcnt(4)" ::: "memory");
        else             asm volatile("s_waitcnt vmcnt(0)" ::: "memory");
        __builtin_amdgcn_s_barrier();
        __builtin_amdgcn_sched_barrier(0);

        // ---- odd step s0+1: ic 64..127 from buf[(s0+1)%3]
        if (s0 + 3 < NS) stageH(s0 + 3);
        {
            const unsigned short* cur = Xs + ((s0 + 1) % 3) * CHB;
#pragma unroll
            for (int tap = 0; tap < 9; ++tap) {
                const int dyy = tap / 3, dxx = tap % 3;
                const int lc0 = wp + l15 + dxx;
#pragma unroll
                for (int i2 = 0; i2 < 2; ++i2) {
                    const int off0 = ((dyy * 66 + lc0) * 8 + ((i2 * 4 + kg) ^ (lc0 & 7))) * 8;
                    v8s b0 = *(const v8s*)(cur + off0);
                    v8s b1 = *(const v8s*)(cur + off0 + 16 * 64);
                    acc[0] = __builtin_amdgcn_mfma_f32_16x16x32_bf16(av[tap][2 + i2], b0, acc[0], 0, 0, 0);
                    acc[1] = __builtin_amdgcn_mfma_f32_16x16x32_bf16(av[tap][2 + i2], b1, acc[1], 0, 0, 0);
                }
            }
        }
        if (s0 + 3 < NS) asm volatile("s_waitcnt vmcnt(4)" ::: "memory");
        else             asm volatile("s_waitcnt vmcnt(0)" ::: "memory");

        // ---- epilogue: granule-v1 stores for tile t
        {
            const int pt   = pg + NPG * t;
            const int n    = pt >> 10;
            const int hrow = (pt >> 2) & 255;
            const int w0   = (pt & 3) * 64;
            const size_t gb = (size_t)(hrow & 1) * 16777216 + (size_t)n * 2097152
                            + (size_t)(hrow >> 1) * 256;
#pragma unroll
            for (int ps = 0; ps < 2; ++ps) {
                const int px = wp + ps * 16 + l15;
                const int wc = w0 + px;
                const int ocb = ocq * 16 + kg * 4;
                size_t gaddr = gb + (size_t)(wc >> 2) * 32768
                             + (size_t)((wc & 3) * 64 + ocb);
                v4u pk;
#pragma unroll
                for (int r = 0; r < 4; ++r) pk[r] = f2bfbits(acc[ps][r]);
                *(v4u*)(outp + gaddr) = pk;
            }
        }

        __builtin_amdgcn_s_barrier();
        __builtin_amdgcn_sched_barrier(0);
    }
}

// ---------------------------------------------------------------------------
// per-channel stats over bf16 [P][C] (pixel order irrelevant -> granule-safe)
// ---------------------------------------------------------------------------
template<int C, int OFF>
__global__ __launch_bounds__(256) void statsN(const unsigned short* __restrict__ in, int P)
{
    constexpr int G = C / 8;
    constexpr int LG = (G == 16) ? 4 : 3;
    __shared__ float red[256 * 8];
    const int tid = threadIdx.x;
    const int cg = tid & (G - 1);
    float s[8], q[8];
#pragma unroll
    for (int j = 0; j < 8; ++j) { s[j] = 0.f; q[j] = 0.f; }
    const int tot = P * G;
    const int stride = gridDim.x * 256;
    for (int i = blockIdx.x * 256 + tid; i < tot; i += stride) {
        const int p = i >> LG;
        v8s v = *(const v8s*)(in + (size_t)p * C + cg * 8);
#pragma unroll
        for (int j = 0; j < 8; ++j) {
            float f = bfbits2f((unsigned short)v[j]);
            s[j] += f; q[j] = fmaf(f, f, q[j]);
        }
    }
#pragma unroll
    for (int j = 0; j < 8; ++j) red[tid * 8 + j] = s[j];
    __syncthreads();
    for (int st = (256 / G) >> 1; st > 0; st >>= 1) {
        if ((tid >> LG) < st)
#pragma unroll
            for (int j = 0; j < 8; ++j) red[tid * 8 + j] += red[(tid + st * G) * 8 + j];
        __syncthreads();
    }
    if (tid < G)
#pragma unroll
        for (int j = 0; j < 8; ++j) atomicAdd(&g_stats[OFF + 2 * (cg * 8 + j)], red[tid * 8 + j]);
    __syncthreads();
#pragma unroll
    for (int j = 0; j < 8; ++j) red[tid * 8 + j] = q[j];
    __syncthreads();
    for (int st = (256 / G) >> 1; st > 0; st >>= 1) {
        if ((tid >> LG) < st)
#pragma unroll
            for (int j = 0; j < 8; ++j) red[tid * 8 + j] += red[(tid + st * G) * 8 + j];
        __syncthreads();
    }
    if (tid < G)
#pragma unroll
        for (int j = 0; j < 8; ++j) atomicAdd(&g_stats[OFF + 2 * (cg * 8 + j) + 1], red[tid * 8 + j]);
}

// ---------------------------------------------------------------------------
// BN + mish over NHWC bf16, 8 elems/thread (bn1)
// ---------------------------------------------------------------------------
template<int C, int OFF>
__global__ __launch_bounds__(256) void bnN(const unsigned short* __restrict__ in,
                                           unsigned short* __restrict__ outp,
                                           const float* __restrict__ gam,
                                           const float* __restrict__ bet, int total8)
{
    const int t0 = blockIdx.x * 256 + threadIdx.x;
    const int c0 = (t0 * 8) & (C - 1);
    float sc[8], sh[8];
#pragma unroll
    for (int j = 0; j < 8; ++j) {
        int c = c0 + j;
        float m  = g_stats[OFF + 2 * c] * INV_CNT;
        float va = fmaf(g_stats[OFF + 2 * c + 1], INV_CNT, -m * m);
        sc[j] = rsqrtf(va + EPS_) * gam[c];
        sh[j] = fmaf(-m, sc[j], bet[c]);
    }
    const int stride = gridDim.x * 256;
    for (int i = t0; i < total8; i += stride) {
        v8s v = *(const v8s*)(in + (size_t)i * 8);
        v8s o;
#pragma unroll
        for (int j = 0; j < 8; ++j)
            o[j] = (short)f2bfbits(mishf(fmaf(bfbits2f((unsigned short)v[j]), sc[j], sh[j])));
        *(v8s*)(outp + (size_t)i * 8) = o;
    }
}

// ---------------------------------------------------------------------------
// haarFused v3 (proven 143 µs): bn2+mish + bf16 NHWC residual (xh) -> Haar ->
// cA + MFMA 1x1 (192->64) -> convh raw + fused statsH. c2 read from d_out in
// granule-v1; every granule this block reads is clobbered only by this block's
// own stores, all issued after the first __syncthreads.
// Block: 512 thr, one lowres row (128 px). Grid 1024 = 8 n x 128 rows.
// ---------------------------------------------------------------------------
__global__ __launch_bounds__(512) void haarFused(const unsigned short* c2,
                                                 const unsigned short* __restrict__ xh,
                                                 const float* __restrict__ g2,
                                                 const float* __restrict__ be2,
                                                 float* out_low,
                                                 float* convh)
{
    __shared__ __align__(16) unsigned short Bs[128 * 192];   // 49152 B; Cf overlays
    const int tid = threadIdx.x, lane = tid & 63;
    const int n = blockIdx.x >> 7, row = blockIdx.x & 127;

    const int wv = tid >> 6;
    const int ocw = wv >> 2, wp = (wv & 3) * 32;
    const int l15 = lane & 15, kg = lane >> 4;

    // ---- phase A: loads + bn2+mish+residual + haar (NO global stores yet)
    const int px = tid >> 2, cg = tid & 3;
    float low[16];
    v8s Hb[2], Vb[2], Db[2];
    {
        float sc[16], sh[16];
#pragma unroll
        for (int j = 0; j < 16; ++j) {
            int c = cg * 16 + j;
            float m  = g_stats[256 + 2 * c] * INV_CNT;
            float va = fmaf(g_stats[256 + 2 * c + 1], INV_CNT, -m * m);
            sc[j] = rsqrtf(va + EPS_) * g2[c];
            sh[j] = fmaf(-m, sc[j], be2[c]);
        }
        // c2 granule-v1 reads: pixel (2row+i, 2px+m), ch cg*16 + [0,16)
        const size_t cbase = (size_t)n * 2097152 + (size_t)(px >> 1) * 32768
                           + (size_t)row * 256 + (px & 1) * 128 + cg * 16;
        const size_t xbase = ((size_t)n * 65536 + (size_t)(2 * row) * 256 + 2 * px) * 64 + cg * 16;
        v8s cv[2][2][2], xv[2][2][2];
#pragma unroll
        for (int i = 0; i < 2; ++i)
#pragma unroll
            for (int m = 0; m < 2; ++m) {
                const unsigned short* cp = c2 + cbase + (size_t)i * 16777216 + m * 64;
                cv[i][m][0] = *(const v8s*)cp;
                cv[i][m][1] = *(const v8s*)(cp + 8);
                const unsigned short* xp = xh + xbase + i * 16384 + m * 64;
                xv[i][m][0] = *(const v8s*)xp;
                xv[i][m][1] = *(const v8s*)(xp + 8);
            }
#pragma unroll
        for (int jj = 0; jj < 2; ++jj)
#pragma unroll
            for (int j = 0; j < 8; ++j) {
                const int jc = jj * 8 + j;
                float y00 = mishf(fmaf(bfbits2f((unsigned short)cv[0][0][jj][j]), sc[jc], sh[jc]))
                          + bfbits2f((unsigned short)xv[0][0][jj][j]);
                float y01 = mishf(fmaf(bfbits2f((unsigned short)cv[0][1][jj][j]), sc[jc], sh[jc]))
                          + bfbits2f((unsigned short)xv[0][1][jj][j]);
                float y10 = mishf(fmaf(bfbits2f((unsigned short)cv[1][0][jj][j]), sc[jc], sh[jc]))
                          + bfbits2f((unsigned short)xv[1][0][jj][j]);
                float y11 = mishf(fmaf(bfbits2f((unsigned short)cv[1][1][jj][j]), sc[jc], sh[jc]))
                          + bfbits2f((unsigned short)xv[1][1][jj][j]);
                low[jc] = 0.5f * (y00 + y01 + y10 + y11);
                Hb[jj][j] = (short)f2bfbits(0.5f * (y00 + y01 - y10 - y11));
                Vb[jj][j] = (short)f2bfbits(0.5f * (y00 - y01 + y10 - y11));
                Db[jj][j] = (short)f2bfbits(0.5f * (y00 - y01 - y10 + y11));
            }
        unsigned short* bp = Bs + px * 192;
        const int sx = px & 7;
#pragma unroll
        for (int jj = 0; jj < 2; ++jj) {
            *(v8s*)(bp + (((cg * 2 + jj) ^ sx) << 3))      = Hb[jj];
            *(v8s*)(bp + (((8 + cg * 2 + jj) ^ sx) << 3))  = Vb[jj];
            *(v8s*)(bp + (((16 + cg * 2 + jj) ^ sx) << 3)) = Db[jj];
        }
    }
    __syncthreads();   // all c2 reads consumed block-wide; Bs ready

    // ---- out_low stores (clobber this block's own r=0 granules — now safe)
#pragma unroll
    for (int j = 0; j < 16; ++j) {
        const int c = cg * 16 + j;
        out_low[((size_t)(n * 64 + c) << 14) + row * 128 + px] = low[j];
    }

    // ---- A fragments (whT, L2-hot)
    v8s av2[6][2];
    {
        const unsigned short* wb = g_whT + (size_t)(ocw * 32 + l15) * 192 + kg * 8;
#pragma unroll
        for (int s = 0; s < 6; ++s)
#pragma unroll
            for (int sub = 0; sub < 2; ++sub)
                av2[s][sub] = *(const v8s*)(wb + (size_t)sub * 16 * 192 + s * 32);
    }

    // ---- phase B: MFMA, K=192 (6 steps)
    v4f acc[2][2];
    {
        v4f z = {0.f, 0.f, 0.f, 0.f};
        acc[0][0] = z; acc[0][1] = z; acc[1][0] = z; acc[1][1] = z;
    }
    {
        const int pix0 = wp + l15;
        const unsigned short* bbase = Bs + pix0 * 192;
        const int sx0 = pix0 & 7;
#pragma unroll
        for (int s = 0; s < 6; ++s) {
            const int ck = s * 4 + kg;
            v8s b0 = *(const v8s*)(bbase + ((ck ^ sx0) << 3));
            v8s b1 = *(const v8s*)(bbase + 16 * 192 + ((ck ^ sx0) << 3));
            acc[0][0] = __builtin_amdgcn_mfma_f32_16x16x32_bf16(av2[s][0], b0, acc[0][0], 0, 0, 0);
            acc[1][0] = __builtin_amdgcn_mfma_f32_16x16x32_bf16(av2[s][1], b0, acc[1][0], 0, 0, 0);
            acc[0][1] = __builtin_amdgcn_mfma_f32_16x16x32_bf16(av2[s][0], b1, acc[0][1], 0, 0, 0);
            acc[1][1] = __builtin_amdgcn_mfma_f32_16x16x32_bf16(av2[s][1], b1, acc[1][1], 0, 0, 0);
        }
    }

    // ---- phase C: Cf [64 oc][130 px] f32 (overlay Bs) -> coalesced NCHW + stats
    __syncthreads();
    float* Cf = (float*)Bs;
#pragma unroll
    for (int sub = 0; sub < 2; ++sub)
#pragma unroll
        for (int ps = 0; ps < 2; ++ps) {
            const int pxe = wp + ps * 16 + l15;
            const int ocb = ocw * 32 + sub * 16 + kg * 4;
#pragma unroll
            for (int r = 0; r < 4; ++r)
                Cf[(ocb + r) * 130 + pxe] = acc[sub][ps][r];
        }
    __syncthreads();
    {
        const int oc = tid >> 3, seg = tid & 7;
        float vals[16];
        float S = 0.f, Q = 0.f;
#pragma unroll
        for (int i = 0; i < 16; ++i) {
            float f = Cf[oc * 130 + seg * 16 + i];
            vals[i] = f; S += f; Q = fmaf(f, f, Q);
        }
        float* gp = convh + ((size_t)(n * 64 + oc) << 14) + row * 128 + seg * 16;
#pragma unroll
        for (int i4 = 0; i4 < 4; ++i4) {
            float4 t4;
            t4.x = vals[i4*4]; t4.y = vals[i4*4+1]; t4.z = vals[i4*4+2]; t4.w = vals[i4*4+3];
            *(float4*)(gp + i4 * 4) = t4;
        }
        S += __shfl_down(S, 4); Q += __shfl_down(Q, 4);
        S += __shfl_down(S, 2); Q += __shfl_down(Q, 2);
        S += __shfl_down(S, 1); Q += __shfl_down(Q, 1);
        if (seg == 0) {
            atomicAdd(&g_stats[384 + 2 * oc],     S);
            atomicAdd(&g_stats[384 + 2 * oc + 1], Q);
        }
    }
}

// ---------------------------------------------------------------------------
// final BN+mish on convh (NCHW f32), in place
// ---------------------------------------------------------------------------
__global__ __launch_bounds__(256) void bnF(const float* __restrict__ in,
                                           float* __restrict__ outp, int stOff,
                                           const float* __restrict__ gam,
                                           const float* __restrict__ bet,
                                           int Cmask, int logHW, float invCnt, int total4)
{
    int t = blockIdx.x * 256 + threadIdx.x;
    if (t >= total4) return;
    int idx = t << 2;
    int c = (idx >> logHW) & Cmask;
    float mean = g_stats[stOff + 2 * c] * invCnt;
    float var = fmaf(g_stats[stOff + 2 * c + 1], invCnt, -mean * mean);
    float scale = rsqrtf(var + EPS_) * gam[c];
    float shift = fmaf(-mean, scale, bet[c]);
    float4 v = *(const float4*)(in + idx);
    v.x = mishf(fmaf(v.x, scale, shift));
    v.y = mishf(fmaf(v.y, scale, shift));
    v.z = mishf(fmaf(v.z, scale, shift));
    v.w = mishf(fmaf(v.w, scale, shift));
    *(float4*)(outp + idx) = v;
}

// ---------------------------------------------------------------------------
extern "C" void kernel_launch(void* const* d_in, const int* in_sizes, int n_in,
                              void* d_out, int out_size, void* d_ws, size_t ws_size,
                              hipStream_t stream)
{
    (void)in_sizes; (void)n_in; (void)out_size; (void)ws_size;

    const float* x   = (const float*)d_in[0];
    const float* w1  = (const float*)d_in[1];
    const float* g1  = (const float*)d_in[3];
    const float* be1 = (const float*)d_in[4];
    const float* w2  = (const float*)d_in[5];
    const float* g2  = (const float*)d_in[7];
    const float* be2 = (const float*)d_in[8];
    const float* wh  = (const float*)d_in[9];
    const float* gh  = (const float*)d_in[11];
    const float* beh = (const float*)d_in[12];
    // biases b1,b2,bh are mathematically absorbed by the following BatchNorms.

    char* ws = (char*)d_ws;
    unsigned short* xh = (unsigned short*)ws;                 // x NHWC bf16 (stays live)
    unsigned short* h1 = (unsigned short*)(ws + 67108864);    // conv1 out NHWC bf16
    unsigned short* c2 = (unsigned short*)d_out;              // conv2 raw bf16, granule-v1 in d_out
    float* out_low = (float*)d_out;
    float* convh   = (float*)d_out + 8388608;

    prep<<<288, 256, 0, stream>>>(w1, w2, wh);
    transpose_x<<<8192, 256, 0, stream>>>(x, xh);

    // conv1: xh -> h1 raw (64-px tiles, 128 oc/block, 3-deep counted-vmcnt)
    conv1MFMA<<<1024, 512, 0, stream>>>(xh, h1, 8);
    statsN<128, 0><<<2048, 256, 0, stream>>>(h1, 524288);
    bnN<128, 0><<<1024, 256, 0, stream>>>(h1, h1, g1, be1, 8388608);
    // conv2 single-pass: h1 -> c2 (granule-v1; 3-deep counted-vmcnt)
    conv2MFMA<<<2048, 512, 0, stream>>>(h1, c2, 4);
    statsN<64, 256><<<1024, 256, 0, stream>>>(c2, 524288);
    // bn2+mish+residual(xh) + haar + 1x1 MFMA (+statsH fused)
    haarFused<<<1024, 512, 0, stream>>>(c2, xh, g2, be2, out_low, convh);
    // final bn+mish on convh
    bnF<<<8192, 256, 0, stream>>>(convh, convh, 384, gh, beh, 63, 14, 1.f / 131072.f, 2097152);
}

// Round 17
// 1045.797 us; speedup vs baseline: 1.6279x; 1.6279x over previous
//
#include <hip/hip_runtime.h>
#include <hip/hip_bf16.h>

#define DEV static __device__ __forceinline__

typedef short v8s __attribute__((ext_vector_type(8)));
typedef float v4f __attribute__((ext_vector_type(4)));
typedef unsigned short v4u __attribute__((ext_vector_type(4)));

constexpr int N_ = 8;
constexpr float EPS_ = 1e-5f;
constexpr float INV_CNT = 1.f / 524288.f;   // 1/(8*256*256)
constexpr int CHB = 12800;                  // ushorts per staging buffer (25600 B)

// g_part layout: stats1 partials [0, 262144) = 1024 blk x 256
//                stats2 partials [262144, 327680) = 512 blk x 128
//                statsH partials [327680, 458752) = 1024 blk x 128
constexpr int PB1 = 0;
constexpr int PB2 = 262144;
constexpr int PBH = 327680;

// c2 granule layout v1 (block-private aliasing with d_out, full-row haar blocks):
//   element (n, hr, wc, ch), r=hr&1, row=hr>>1  ->  ushort offset
//   r*16777216 + n*2097152 + (wc>>2)*32768 + row*256 + (wc&3)*64 + ch

// device-global scratch
__device__ __align__(16) unsigned short g_wT1[9*128*64];   // [tap][oc][ic] bf16
__device__ __align__(16) unsigned short g_wT2[9*64*128];
__device__ __align__(16) unsigned short g_whT[64*192];     // [oc][k] bf16
__device__ __align__(16) float g_stats[512];               // s1[0:256) s2[256:384) sH[384:512)
__device__ __align__(16) float g_part[458752];             // per-block stats partials
__device__ __align__(16) unsigned short g_zero[64];

DEV float bfbits2f(unsigned short u) { return __uint_as_float(((unsigned)u) << 16); }
DEV unsigned short f2bfbits(float f) {
    __hip_bfloat16 h = __float2bfloat16(f);
    unsigned short b;
    __builtin_memcpy(&b, &h, 2);
    return b;
}

DEV float mishf(float v) {
    // mish(v) = v * t(t+2)/(t(t+2)+2), t = e^v
    float t = __expf(fminf(v, 30.f));
    float num = fmaf(t, t, 2.f * t);
    return v * num * __builtin_amdgcn_rcpf(num + 2.f);
}

DEV void gll16(const unsigned short* g, unsigned short* l) {
    __builtin_amdgcn_global_load_lds(
        (const __attribute__((address_space(1))) unsigned int*)g,
        (__attribute__((address_space(3))) unsigned int*)l,
        16, 0, 0);
}

// ---------------------------------------------------------------------------
// prep: weight reorders (bf16) + zero stats + zero page
// ---------------------------------------------------------------------------
__global__ __launch_bounds__(256) void prep(const float* __restrict__ w1,
                                            const float* __restrict__ w2,
                                            const float* __restrict__ wh)
{
    int idx = blockIdx.x * 256 + threadIdx.x;
    if (idx < 512) g_stats[idx] = 0.f;
    if (idx < 64) g_zero[idx] = 0;
    if (idx < 12288) g_whT[idx] = f2bfbits(wh[idx]);       // [oc][192] == OIHW flat
    if (idx < 73728) {
        int tap = idx / 8192, rem = idx & 8191;
        {   int oc = rem >> 6, ic = rem & 63;
            g_wT1[idx] = f2bfbits(w1[(oc * 64 + ic) * 9 + tap]); }
        {   int oc = rem >> 7, ic = rem & 127;
            g_wT2[idx] = f2bfbits(w2[(oc * 128 + ic) * 9 + tap]); }
    }
}

// ---------------------------------------------------------------------------
// transpose x: NCHW f32 -> NHWC bf16
// ---------------------------------------------------------------------------
__global__ __launch_bounds__(256) void transpose_x(const float* __restrict__ x,
                                                   unsigned short* __restrict__ xh)
{
    __shared__ float t[64][65];
    const int tid = threadIdx.x;
    const int bid = blockIdx.x;
    const int n = bid >> 10, pb = bid & 1023;
    const size_t pix0 = (size_t)pb * 64;
    const float* xb = x + ((size_t)n << 22) + pix0;
#pragma unroll
    for (int cb = 0; cb < 4; ++cb) {
        int c = (tid >> 4) + cb * 16;
        int p = (tid & 15) * 4;
        float4 v = *(const float4*)(xb + ((size_t)c << 16) + p);
        t[c][p] = v.x; t[c][p+1] = v.y; t[c][p+2] = v.z; t[c][p+3] = v.w;
    }
    __syncthreads();
    unsigned short* ob = xh + (((size_t)n << 16) + pix0) * 64;
#pragma unroll
    for (int pb2 = 0; pb2 < 2; ++pb2) {
        int p = (tid >> 3) + pb2 * 32;
        int c0 = (tid & 7) * 8;
        v8s r;
#pragma unroll
        for (int i = 0; i < 8; ++i) r[i] = (short)f2bfbits(t[c0 + i][p]);
        *(v8s*)(ob + (size_t)p * 64 + c0) = r;
    }
}

// ---------------------------------------------------------------------------
// conv1: MFMA 3x3, pad=1, NHWC bf16, 64ic -> 128oc. 64-px tiles, all 128 oc.
// 3-deep counted-vmcnt pipeline (R14, best measured).
// Block 512 thr = 8 waves = 4 ocw x 2 pxg; wave 32 oc x 32 px.
// ---------------------------------------------------------------------------
__global__ __launch_bounds__(512, 2) void conv1MFMA(const unsigned short* __restrict__ in,
                                                    unsigned short* __restrict__ outp,
                                                    const int nTiles)
{
    __shared__ __align__(16) unsigned short Xs[3 * CHB + 512];   // 77824 B
    const int tid  = threadIdx.x;
    const int lane = tid & 63;
    const int wv   = tid >> 6;
    const int pg   = (int)blockIdx.x;
    const int NPG  = (int)gridDim.x;

    const int ocw = wv >> 1;              // 0..3 (32-oc group)
    const int wp  = (wv & 1) * 32;        // wave pixel offset
    const int l15 = lane & 15, kg = lane >> 4;

    v8s av[9][2][2];
    {
        const unsigned short* wb =
            g_wT1 + ((size_t)(ocw * 32 + l15)) * 64 + kg * 8;
#pragma unroll
        for (int tap = 0; tap < 9; ++tap)
#pragma unroll
            for (int ics = 0; ics < 2; ++ics)
#pragma unroll
                for (int sub = 0; sub < 2; ++sub)
                    av[tap][ics][sub] =
                        *(const v8s*)(wb + ((size_t)tap * 128 + sub * 16) * 64 + ics * 32);
    }

    auto stage = [&](int s) {
        const int pt   = pg + NPG * s;
        const int n    = pt >> 10;
        const int hrow = (pt >> 2) & 255;
        const int w0   = (pt & 3) * 64;
        unsigned short* buf = Xs + (s % 3) * CHB;
#pragma unroll
        for (int it = 0; it < 4; ++it) {
            const int cb = it * 512 + wv * 64;               // wave-uniform
            unsigned short* dst = (cb >= 1600) ? (Xs + 3 * CHB)
                                               : (buf + (size_t)cb * 8);
            const int chunk = cb + lane;
            int r   = chunk / 528;
            int rem = chunk - r * 528;
            int lc  = rem >> 3, k = rem & 7;
            int gr  = hrow - 1 + r;
            int gc  = w0 - 1 + lc;
            const unsigned short* src;
            if ((chunk < 1584) & ((unsigned)gr < 256u) & ((unsigned)gc < 256u))
                src = in + ((((size_t)n << 16) + ((size_t)gr << 8) + gc) * 64)
                         + ((k ^ (lc & 7)) << 3);
            else
                src = g_zero;
            gll16(src, dst);                                 // always issued: 4/wave
        }
    };

    stage(0);
    stage(1);
    asm volatile("s_waitcnt vmcnt(4)" ::: "memory");   // drain stage(0) (+av)
    __builtin_amdgcn_s_barrier();
    __builtin_amdgcn_sched_barrier(0);

    for (int s = 0; s < nTiles; ++s) {
        if (s + 2 < nTiles) stage(s + 2);                // fly across 2 barriers

        const unsigned short* cur = Xs + (s % 3) * CHB;
        const int pt   = pg + NPG * s;
        const int n    = pt >> 10;
        const int hrow = (pt >> 2) & 255;
        const int w0   = (pt & 3) * 64;
        const size_t pixbase = ((size_t)n << 16) + ((size_t)hrow << 8) + w0;

        v4f acc[2][2];
        {
            v4f z = {0.f, 0.f, 0.f, 0.f};
            acc[0][0] = z; acc[0][1] = z; acc[1][0] = z; acc[1][1] = z;
        }
#pragma unroll
        for (int tap = 0; tap < 9; ++tap) {
            const int dyy = tap / 3, dxx = tap % 3;
            const int lc0 = wp + l15 + dxx;
#pragma unroll
            for (int ics = 0; ics < 2; ++ics) {
                const int off0 = ((dyy * 66 + lc0) * 8 + ((ics * 4 + kg) ^ (lc0 & 7))) * 8;
                v8s b0 = *(const v8s*)(cur + off0);
                v8s b1 = *(const v8s*)(cur + off0 + 16 * 64);   // lc0+16: same (lc&7)
                acc[0][0] = __builtin_amdgcn_mfma_f32_16x16x32_bf16(av[tap][ics][0], b0, acc[0][0], 0, 0, 0);
                acc[1][0] = __builtin_amdgcn_mfma_f32_16x16x32_bf16(av[tap][ics][1], b0, acc[1][0], 0, 0, 0);
                acc[0][1] = __builtin_amdgcn_mfma_f32_16x16x32_bf16(av[tap][ics][0], b1, acc[0][1], 0, 0, 0);
                acc[1][1] = __builtin_amdgcn_mfma_f32_16x16x32_bf16(av[tap][ics][1], b1, acc[1][1], 0, 0, 0);
            }
        }

        if (s + 2 < nTiles) asm volatile("s_waitcnt vmcnt(4)" ::: "memory");
        else                asm volatile("s_waitcnt vmcnt(0)" ::: "memory");

#pragma unroll
        for (int sub = 0; sub < 2; ++sub)
#pragma unroll
            for (int ps = 0; ps < 2; ++ps) {
                const int px  = wp + ps * 16 + l15;
                const int ocb = ocw * 32 + sub * 16 + kg * 4;
                size_t gaddr = (pixbase + px) * 128 + ocb;
                v4f a = acc[sub][ps];
                v4u pk;
#pragma unroll
                for (int r = 0; r < 4; ++r) pk[r] = f2bfbits(a[r]);
                *(v4u*)(outp + gaddr) = pk;
            }

        __builtin_amdgcn_s_barrier();
        __builtin_amdgcn_sched_barrier(0);
    }
}

// ---------------------------------------------------------------------------
// conv2: single-pass MFMA 3x3, 128ic -> 64oc, granule-v1 output.
// 3-deep counted-vmcnt pipeline over (tile, ic-half) steps; static halves.
// Block 512 thr = 8 waves = 4 ocq x 2 pxg; wave 16 oc x 32 px.
// ---------------------------------------------------------------------------
__global__ __launch_bounds__(512, 2) void conv2MFMA(const unsigned short* __restrict__ in,
                                                    unsigned short* __restrict__ outp,
                                                    const int nTiles)
{
    __shared__ __align__(16) unsigned short Xs[3 * CHB + 512];   // 77824 B
    const int tid  = threadIdx.x;
    const int lane = tid & 63;
    const int wv   = tid >> 6;
    const int pg   = (int)blockIdx.x;
    const int NPG  = (int)gridDim.x;

    const int ocq = wv >> 1;              // 0..3 (16-oc group)
    const int wp  = (wv & 1) * 32;
    const int l15 = lane & 15, kg = lane >> 4;

    v8s av[9][4];
    {
        const unsigned short* wb =
            g_wT2 + ((size_t)(ocq * 16 + l15)) * 128 + kg * 8;
#pragma unroll
        for (int tap = 0; tap < 9; ++tap)
#pragma unroll
            for (int ics = 0; ics < 4; ++ics)
                av[tap][ics] = *(const v8s*)(wb + (size_t)tap * 64 * 128 + ics * 32);
    }

    auto stageH = [&](int s) {            // step s: tile s>>1, ic-half s&1
        const int tt    = s >> 1;
        const int icoff = (s & 1) * 64;
        const int pt   = pg + NPG * tt;
        const int n    = pt >> 10;
        const int hrow = (pt >> 2) & 255;
        const int w0   = (pt & 3) * 64;
#pragma unroll
        for (int it = 0; it < 4; ++it) {
            const int cb = it * 512 + wv * 64;
            unsigned short* buf = Xs + (s % 3) * CHB;
            unsigned short* dst = (cb >= 1600) ? (Xs + 3 * CHB)
                                               : (buf + (size_t)cb * 8);
            const int chunk = cb + lane;
            int r   = chunk / 528;
            int rem = chunk - r * 528;
            int lc  = rem >> 3, k = rem & 7;
            int gr  = hrow - 1 + r;
            int gc  = w0 - 1 + lc;
            const unsigned short* src;
            if ((chunk < 1584) & ((unsigned)gr < 256u) & ((unsigned)gc < 256u))
                src = in + ((((size_t)n << 16) + ((size_t)gr << 8) + gc) * 128)
                         + icoff + ((k ^ (lc & 7)) << 3);
            else
                src = g_zero;
            gll16(src, dst);
        }
    };

    const int NS = nTiles * 2;
    stageH(0);
    stageH(1);
    asm volatile("s_waitcnt vmcnt(4)" ::: "memory");
    __builtin_amdgcn_s_barrier();
    __builtin_amdgcn_sched_barrier(0);

    for (int t = 0; t < nTiles; ++t) {
        const int s0 = 2 * t;
        v4f acc[2];
        {
            v4f z = {0.f, 0.f, 0.f, 0.f};
            acc[0] = z; acc[1] = z;
        }

        // ---- even step s0: ic 0..63 from buf[s0%3]
        if (s0 + 2 < NS) stageH(s0 + 2);
        {
            const unsigned short* cur = Xs + (s0 % 3) * CHB;
#pragma unroll
            for (int tap = 0; tap < 9; ++tap) {
                const int dyy = tap / 3, dxx = tap % 3;
                const int lc0 = wp + l15 + dxx;
#pragma unroll
                for (int i2 = 0; i2 < 2; ++i2) {
                    const int off0 = ((dyy * 66 + lc0) * 8 + ((i2 * 4 + kg) ^ (lc0 & 7))) * 8;
                    v8s b0 = *(const v8s*)(cur + off0);
                    v8s b1 = *(const v8s*)(cur + off0 + 16 * 64);
                    acc[0] = __builtin_amdgcn_mfma_f32_16x16x32_bf16(av[tap][i2], b0, acc[0], 0, 0, 0);
                    acc[1] = __builtin_amdgcn_mfma_f32_16x16x32_bf16(av[tap][i2], b1, acc[1], 0, 0, 0);
                }
            }
        }
        if (s0 + 2 < NS) asm volatile("s_waitcnt vmcnt(4)" ::: "memory");
        else             asm volatile("s_waitcnt vmcnt(0)" ::: "memory");
        __builtin_amdgcn_s_barrier();
        __builtin_amdgcn_sched_barrier(0);

        // ---- odd step s0+1: ic 64..127 from buf[(s0+1)%3]
        if (s0 + 3 < NS) stageH(s0 + 3);
        {
            const unsigned short* cur = Xs + ((s0 + 1) % 3) * CHB;
#pragma unroll
            for (int tap = 0; tap < 9; ++tap) {
                const int dyy = tap / 3, dxx = tap % 3;
                const int lc0 = wp + l15 + dxx;
#pragma unroll
                for (int i2 = 0; i2 < 2; ++i2) {
                    const int off0 = ((dyy * 66 + lc0) * 8 + ((i2 * 4 + kg) ^ (lc0 & 7))) * 8;
                    v8s b0 = *(const v8s*)(cur + off0);
                    v8s b1 = *(const v8s*)(cur + off0 + 16 * 64);
                    acc[0] = __builtin_amdgcn_mfma_f32_16x16x32_bf16(av[tap][2 + i2], b0, acc[0], 0, 0, 0);
                    acc[1] = __builtin_amdgcn_mfma_f32_16x16x32_bf16(av[tap][2 + i2], b1, acc[1], 0, 0, 0);
                }
            }
        }
        if (s0 + 3 < NS) asm volatile("s_waitcnt vmcnt(4)" ::: "memory");
        else             asm volatile("s_waitcnt vmcnt(0)" ::: "memory");

        // ---- epilogue: granule-v1 stores for tile t
        {
            const int pt   = pg + NPG * t;
            const int n    = pt >> 10;
            const int hrow = (pt >> 2) & 255;
            const int w0   = (pt & 3) * 64;
            const size_t gb = (size_t)(hrow & 1) * 16777216 + (size_t)n * 2097152
                            + (size_t)(hrow >> 1) * 256;
#pragma unroll
            for (int ps = 0; ps < 2; ++ps) {
                const int px = wp + ps * 16 + l15;
                const int wc = w0 + px;
                const int ocb = ocq * 16 + kg * 4;
                size_t gaddr = gb + (size_t)(wc >> 2) * 32768
                             + (size_t)((wc & 3) * 64 + ocb);
                v4u pk;
#pragma unroll
                for (int r = 0; r < 4; ++r) pk[r] = f2bfbits(acc[ps][r]);
                *(v4u*)(outp + gaddr) = pk;
            }
        }

        __builtin_amdgcn_s_barrier();
        __builtin_amdgcn_sched_barrier(0);
    }
}

// ---------------------------------------------------------------------------
// statsP: per-channel sum/sumsq partials over bf16 [P][C] -> g_part (NO atomics)
// ---------------------------------------------------------------------------
template<int C, int PBASE>
__global__ __launch_bounds__(256) void statsP(const unsigned short* __restrict__ in, int P)
{
    constexpr int G = C / 8;
    constexpr int LG = (G == 16) ? 4 : 3;
    __shared__ float red[256 * 8];
    const int tid = threadIdx.x;
    const int cg = tid & (G - 1);
    float s[8], q[8];
#pragma unroll
    for (int j = 0; j < 8; ++j) { s[j] = 0.f; q[j] = 0.f; }
    const int tot = P * G;
    const int stride = gridDim.x * 256;
    for (int i = blockIdx.x * 256 + tid; i < tot; i += stride) {
        const int p = i >> LG;
        v8s v = *(const v8s*)(in + (size_t)p * C + cg * 8);
#pragma unroll
        for (int j = 0; j < 8; ++j) {
            float f = bfbits2f((unsigned short)v[j]);
            s[j] += f; q[j] = fmaf(f, f, q[j]);
        }
    }
#pragma unroll
    for (int j = 0; j < 8; ++j) red[tid * 8 + j] = s[j];
    __syncthreads();
    for (int st = (256 / G) >> 1; st > 0; st >>= 1) {
        if ((tid >> LG) < st)
#pragma unroll
            for (int j = 0; j < 8; ++j) red[tid * 8 + j] += red[(tid + st * G) * 8 + j];
        __syncthreads();
    }
    if (tid < G)
#pragma unroll
        for (int j = 0; j < 8; ++j)
            g_part[PBASE + blockIdx.x * (2 * C) + 2 * (cg * 8 + j)] = red[tid * 8 + j];
    __syncthreads();
#pragma unroll
    for (int j = 0; j < 8; ++j) red[tid * 8 + j] = q[j];
    __syncthreads();
    for (int st = (256 / G) >> 1; st > 0; st >>= 1) {
        if ((tid >> LG) < st)
#pragma unroll
            for (int j = 0; j < 8; ++j) red[tid * 8 + j] += red[(tid + st * G) * 8 + j];
        __syncthreads();
    }
    if (tid < G)
#pragma unroll
        for (int j = 0; j < 8; ++j)
            g_part[PBASE + blockIdx.x * (2 * C) + 2 * (cg * 8 + j) + 1] = red[tid * 8 + j];
}

// ---------------------------------------------------------------------------
// statsR: reduce nparts partial vectors of NV floats -> g_stats[OFF..OFF+NV)
// ---------------------------------------------------------------------------
template<int NV, int PBASE, int OFF>
__global__ __launch_bounds__(256) void statsR(int nparts)
{
    const int v = threadIdx.x;
    if (v < NV) {
        float s = 0.f;
        for (int b = 0; b < nparts; ++b) s += g_part[PBASE + b * NV + v];
        g_stats[OFF + v] = s;
    }
}

// ---------------------------------------------------------------------------
// BN + mish over NHWC bf16, 8 elems/thread (bn1)
// ---------------------------------------------------------------------------
template<int C, int OFF>
__global__ __launch_bounds__(256) void bnN(const unsigned short* __restrict__ in,
                                           unsigned short* __restrict__ outp,
                                           const float* __restrict__ gam,
                                           const float* __restrict__ bet, int total8)
{
    const int t0 = blockIdx.x * 256 + threadIdx.x;
    const int c0 = (t0 * 8) & (C - 1);
    float sc[8], sh[8];
#pragma unroll
    for (int j = 0; j < 8; ++j) {
        int c = c0 + j;
        float m  = g_stats[OFF + 2 * c] * INV_CNT;
        float va = fmaf(g_stats[OFF + 2 * c + 1], INV_CNT, -m * m);
        sc[j] = rsqrtf(va + EPS_) * gam[c];
        sh[j] = fmaf(-m, sc[j], bet[c]);
    }
    const int stride = gridDim.x * 256;
    for (int i = t0; i < total8; i += stride) {
        v8s v = *(const v8s*)(in + (size_t)i * 8);
        v8s o;
#pragma unroll
        for (int j = 0; j < 8; ++j)
            o[j] = (short)f2bfbits(mishf(fmaf(bfbits2f((unsigned short)v[j]), sc[j], sh[j])));
        *(v8s*)(outp + (size_t)i * 8) = o;
    }
}

// ---------------------------------------------------------------------------
// haarFused v3 + partial-store statsH (no atomics): bn2+mish + bf16 residual
// (xh) -> Haar -> cA + MFMA 1x1 (192->64) -> convh raw + statsH partials.
// c2 read from d_out in granule-v1; block-private aliasing as before.
// Block: 512 thr, one lowres row (128 px). Grid 1024 = 8 n x 128 rows.
// ---------------------------------------------------------------------------
__global__ __launch_bounds__(512) void haarFused(const unsigned short* c2,
                                                 const unsigned short* __restrict__ xh,
                                                 const float* __restrict__ g2,
                                                 const float* __restrict__ be2,
                                                 float* out_low,
                                                 float* convh)
{
    __shared__ __align__(16) unsigned short Bs[128 * 192];   // 49152 B; Cf overlays
    const int tid = threadIdx.x, lane = tid & 63;
    const int n = blockIdx.x >> 7, row = blockIdx.x & 127;

    const int wv = tid >> 6;
    const int ocw = wv >> 2, wp = (wv & 3) * 32;
    const int l15 = lane & 15, kg = lane >> 4;

    // ---- phase A: loads + bn2+mish+residual + haar (NO global stores yet)
    const int px = tid >> 2, cg = tid & 3;
    float low[16];
    v8s Hb[2], Vb[2], Db[2];
    {
        float sc[16], sh[16];
#pragma unroll
        for (int j = 0; j < 16; ++j) {
            int c = cg * 16 + j;
            float m  = g_stats[256 + 2 * c] * INV_CNT;
            float va = fmaf(g_stats[256 + 2 * c + 1], INV_CNT, -m * m);
            sc[j] = rsqrtf(va + EPS_) * g2[c];
            sh[j] = fmaf(-m, sc[j], be2[c]);
        }
        // c2 granule-v1 reads: pixel (2row+i, 2px+m), ch cg*16 + [0,16)
        const size_t cbase = (size_t)n * 2097152 + (size_t)(px >> 1) * 32768
                           + (size_t)row * 256 + (px & 1) * 128 + cg * 16;
        const size_t xbase = ((size_t)n * 65536 + (size_t)(2 * row) * 256 + 2 * px) * 64 + cg * 16;
        v8s cv[2][2][2], xv[2][2][2];
#pragma unroll
        for (int i = 0; i < 2; ++i)
#pragma unroll
            for (int m = 0; m < 2; ++m) {
                const unsigned short* cp = c2 + cbase + (size_t)i * 16777216 + m * 64;
                cv[i][m][0] = *(const v8s*)cp;
                cv[i][m][1] = *(const v8s*)(cp + 8);
                const unsigned short* xp = xh + xbase + i * 16384 + m * 64;
                xv[i][m][0] = *(const v8s*)xp;
                xv[i][m][1] = *(const v8s*)(xp + 8);
            }
#pragma unroll
        for (int jj = 0; jj < 2; ++jj)
#pragma unroll
            for (int j = 0; j < 8; ++j) {
                const int jc = jj * 8 + j;
                float y00 = mishf(fmaf(bfbits2f((unsigned short)cv[0][0][jj][j]), sc[jc], sh[jc]))
                          + bfbits2f((unsigned short)xv[0][0][jj][j]);
                float y01 = mishf(fmaf(bfbits2f((unsigned short)cv[0][1][jj][j]), sc[jc], sh[jc]))
                          + bfbits2f((unsigned short)xv[0][1][jj][j]);
                float y10 = mishf(fmaf(bfbits2f((unsigned short)cv[1][0][jj][j]), sc[jc], sh[jc]))
                          + bfbits2f((unsigned short)xv[1][0][jj][j]);
                float y11 = mishf(fmaf(bfbits2f((unsigned short)cv[1][1][jj][j]), sc[jc], sh[jc]))
                          + bfbits2f((unsigned short)xv[1][1][jj][j]);
                low[jc] = 0.5f * (y00 + y01 + y10 + y11);
                Hb[jj][j] = (short)f2bfbits(0.5f * (y00 + y01 - y10 - y11));
                Vb[jj][j] = (short)f2bfbits(0.5f * (y00 - y01 + y10 - y11));
                Db[jj][j] = (short)f2bfbits(0.5f * (y00 - y01 - y10 + y11));
            }
        unsigned short* bp = Bs + px * 192;
        const int sx = px & 7;
#pragma unroll
        for (int jj = 0; jj < 2; ++jj) {
            *(v8s*)(bp + (((cg * 2 + jj) ^ sx) << 3))      = Hb[jj];
            *(v8s*)(bp + (((8 + cg * 2 + jj) ^ sx) << 3))  = Vb[jj];
            *(v8s*)(bp + (((16 + cg * 2 + jj) ^ sx) << 3)) = Db[jj];
        }
    }
    __syncthreads();   // all c2 reads consumed block-wide; Bs ready

    // ---- out_low stores (clobber this block's own r=0 granules — now safe)
#pragma unroll
    for (int j = 0; j < 16; ++j) {
        const int c = cg * 16 + j;
        out_low[((size_t)(n * 64 + c) << 14) + row * 128 + px] = low[j];
    }

    // ---- A fragments (whT, L2-hot)
    v8s av2[6][2];
    {
        const unsigned short* wb = g_whT + (size_t)(ocw * 32 + l15) * 192 + kg * 8;
#pragma unroll
        for (int s = 0; s < 6; ++s)
#pragma unroll
            for (int sub = 0; sub < 2; ++sub)
                av2[s][sub] = *(const v8s*)(wb + (size_t)sub * 16 * 192 + s * 32);
    }

    // ---- phase B: MFMA, K=192 (6 steps)
    v4f acc[2][2];
    {
        v4f z = {0.f, 0.f, 0.f, 0.f};
        acc[0][0] = z; acc[0][1] = z; acc[1][0] = z; acc[1][1] = z;
    }
    {
        const int pix0 = wp + l15;
        const unsigned short* bbase = Bs + pix0 * 192;
        const int sx0 = pix0 & 7;
#pragma unroll
        for (int s = 0; s < 6; ++s) {
            const int ck = s * 4 + kg;
            v8s b0 = *(const v8s*)(bbase + ((ck ^ sx0) << 3));
            v8s b1 = *(const v8s*)(bbase + 16 * 192 + ((ck ^ sx0) << 3));
            acc[0][0] = __builtin_amdgcn_mfma_f32_16x16x32_bf16(av2[s][0], b0, acc[0][0], 0, 0, 0);
            acc[1][0] = __builtin_amdgcn_mfma_f32_16x16x32_bf16(av2[s][1], b0, acc[1][0], 0, 0, 0);
            acc[0][1] = __builtin_amdgcn_mfma_f32_16x16x32_bf16(av2[s][0], b1, acc[0][1], 0, 0, 0);
            acc[1][1] = __builtin_amdgcn_mfma_f32_16x16x32_bf16(av2[s][1], b1, acc[1][1], 0, 0, 0);
        }
    }

    // ---- phase C: Cf [64 oc][130 px] f32 (overlay Bs) -> coalesced NCHW + stats
    __syncthreads();
    float* Cf = (float*)Bs;
#pragma unroll
    for (int sub = 0; sub < 2; ++sub)
#pragma unroll
        for (int ps = 0; ps < 2; ++ps) {
            const int pxe = wp + ps * 16 + l15;
            const int ocb = ocw * 32 + sub * 16 + kg * 4;
#pragma unroll
            for (int r = 0; r < 4; ++r)
                Cf[(ocb + r) * 130 + pxe] = acc[sub][ps][r];
        }
    __syncthreads();
    {
        const int oc = tid >> 3, seg = tid & 7;
        float vals[16];
        float S = 0.f, Q = 0.f;
#pragma unroll
        for (int i = 0; i < 16; ++i) {
            float f = Cf[oc * 130 + seg * 16 + i];
            vals[i] = f; S += f; Q = fmaf(f, f, Q);
        }
        float* gp = convh + ((size_t)(n * 64 + oc) << 14) + row * 128 + seg * 16;
#pragma unroll
        for (int i4 = 0; i4 < 4; ++i4) {
            float4 t4;
            t4.x = vals[i4*4]; t4.y = vals[i4*4+1]; t4.z = vals[i4*4+2]; t4.w = vals[i4*4+3];
            *(float4*)(gp + i4 * 4) = t4;
        }
        S += __shfl_down(S, 4); Q += __shfl_down(Q, 4);
        S += __shfl_down(S, 2); Q += __shfl_down(Q, 2);
        S += __shfl_down(S, 1); Q += __shfl_down(Q, 1);
        if (seg == 0) {
            g_part[PBH + (size_t)blockIdx.x * 128 + 2 * oc]     = S;
            g_part[PBH + (size_t)blockIdx.x * 128 + 2 * oc + 1] = Q;
        }
    }
}

// ---------------------------------------------------------------------------
// final BN+mish on convh (NCHW f32), in place
// ---------------------------------------------------------------------------
__global__ __launch_bounds__(256) void bnF(const float* __restrict__ in,
                                           float* __restrict__ outp, int stOff,
                                           const float* __restrict__ gam,
                                           const float* __restrict__ bet,
                                           int Cmask, int logHW, float invCnt, int total4)
{
    int t = blockIdx.x * 256 + threadIdx.x;
    if (t >= total4) return;
    int idx = t << 2;
    int c = (idx >> logHW) & Cmask;
    float mean = g_stats[stOff + 2 * c] * invCnt;
    float var = fmaf(g_stats[stOff + 2 * c + 1], invCnt, -mean * mean);
    float scale = rsqrtf(var + EPS_) * gam[c];
    float shift = fmaf(-mean, scale, bet[c]);
    float4 v = *(const float4*)(in + idx);
    v.x = mishf(fmaf(v.x, scale, shift));
    v.y = mishf(fmaf(v.y, scale, shift));
    v.z = mishf(fmaf(v.z, scale, shift));
    v.w = mishf(fmaf(v.w, scale, shift));
    *(float4*)(outp + idx) = v;
}

// ---------------------------------------------------------------------------
extern "C" void kernel_launch(void* const* d_in, const int* in_sizes, int n_in,
                              void* d_out, int out_size, void* d_ws, size_t ws_size,
                              hipStream_t stream)
{
    (void)in_sizes; (void)n_in; (void)out_size; (void)ws_size;

    const float* x   = (const float*)d_in[0];
    const float* w1  = (const float*)d_in[1];
    const float* g1  = (const float*)d_in[3];
    const float* be1 = (const float*)d_in[4];
    const float* w2  = (const float*)d_in[5];
    const float* g2  = (const float*)d_in[7];
    const float* be2 = (const float*)d_in[8];
    const float* wh  = (const float*)d_in[9];
    const float* gh  = (const float*)d_in[11];
    const float* beh = (const float*)d_in[12];
    // biases b1,b2,bh are mathematically absorbed by the following BatchNorms.

    char* ws = (char*)d_ws;
    unsigned short* xh = (unsigned short*)ws;                 // x NHWC bf16 (stays live)
    unsigned short* h1 = (unsigned short*)(ws + 67108864);    // conv1 out NHWC bf16
    unsigned short* c2 = (unsigned short*)d_out;              // conv2 raw bf16, granule-v1 in d_out
    float* out_low = (float*)d_out;
    float* convh   = (float*)d_out + 8388608;

    prep<<<288, 256, 0, stream>>>(w1, w2, wh);
    transpose_x<<<8192, 256, 0, stream>>>(x, xh);

    // conv1: xh -> h1 raw (64-px tiles, 128 oc/block, 3-deep counted-vmcnt)
    conv1MFMA<<<1024, 512, 0, stream>>>(xh, h1, 8);
    // stats1: partial reduce (no atomics) + tiny final reduce
    statsP<128, PB1><<<1024, 256, 0, stream>>>(h1, 524288);
    statsR<256, PB1, 0><<<1, 256, 0, stream>>>(1024);
    bnN<128, 0><<<1024, 256, 0, stream>>>(h1, h1, g1, be1, 8388608);
    // conv2 single-pass: h1 -> c2 (granule-v1; 3-deep counted-vmcnt)
    conv2MFMA<<<2048, 512, 0, stream>>>(h1, c2, 4);
    // stats2: partial reduce + final reduce
    statsP<64, PB2><<<512, 256, 0, stream>>>(c2, 524288);
    statsR<128, PB2, 256><<<1, 256, 0, stream>>>(512);
    // bn2+mish+residual(xh) + haar + 1x1 MFMA (+statsH partials)
    haarFused<<<1024, 512, 0, stream>>>(c2, xh, g2, be2, out_low, convh);
    statsR<128, PBH, 384><<<1, 256, 0, stream>>>(1024);
    // final bn+mish on convh
    bnF<<<8192, 256, 0, stream>>>(convh, convh, 384, gh, beh, 63, 14, 1.f / 131072.f, 2097152);
}

// Round 18
// 443.763 us; speedup vs baseline: 3.8364x; 2.3567x over previous
//
#include <hip/hip_runtime.h>
#include <hip/hip_bf16.h>

#define DEV static __device__ __forceinline__

typedef short v8s __attribute__((ext_vector_type(8)));
typedef float v4f __attribute__((ext_vector_type(4)));
typedef unsigned short v4u __attribute__((ext_vector_type(4)));

constexpr int N_ = 8;
constexpr float EPS_ = 1e-5f;
constexpr float INV_CNT = 1.f / 524288.f;   // 1/(8*256*256)
constexpr int CHB = 12800;                  // ushorts per staging buffer (25600 B)

// g_part layout: stats1 partials [0, 262144) = 1024 blk x 256
//                stats2 partials [262144, 327680) = 512 blk x 128
//                statsH partials [327680, 458752) = 1024 blk x 128
constexpr int PB1 = 0;
constexpr int PB2 = 262144;
constexpr int PBH = 327680;

// c2 granule layout v1 (block-private aliasing with d_out, full-row haar blocks):
//   element (n, hr, wc, ch), r=hr&1, row=hr>>1  ->  ushort offset
//   r*16777216 + n*2097152 + (wc>>2)*32768 + row*256 + (wc&3)*64 + ch

// device-global scratch
__device__ __align__(16) unsigned short g_wT1[9*128*64];   // [tap][oc][ic] bf16
__device__ __align__(16) unsigned short g_wT2[9*64*128];
__device__ __align__(16) unsigned short g_whT[64*192];     // [oc][k] bf16
__device__ __align__(16) float g_stats[512];               // s1[0:256) s2[256:384) sH[384:512)
__device__ __align__(16) float g_part[458752];             // per-block stats partials
__device__ __align__(16) unsigned short g_zero[64];

DEV float bfbits2f(unsigned short u) { return __uint_as_float(((unsigned)u) << 16); }
DEV unsigned short f2bfbits(float f) {
    __hip_bfloat16 h = __float2bfloat16(f);
    unsigned short b;
    __builtin_memcpy(&b, &h, 2);
    return b;
}

DEV float mishf(float v) {
    // mish(v) = v * t(t+2)/(t(t+2)+2), t = e^v
    float t = __expf(fminf(v, 30.f));
    float num = fmaf(t, t, 2.f * t);
    return v * num * __builtin_amdgcn_rcpf(num + 2.f);
}

DEV void gll16(const unsigned short* g, unsigned short* l) {
    __builtin_amdgcn_global_load_lds(
        (const __attribute__((address_space(1))) unsigned int*)g,
        (__attribute__((address_space(3))) unsigned int*)l,
        16, 0, 0);
}

// ---------------------------------------------------------------------------
// prep: weight reorders (bf16) + zero stats + zero page
// ---------------------------------------------------------------------------
__global__ __launch_bounds__(256) void prep(const float* __restrict__ w1,
                                            const float* __restrict__ w2,
                                            const float* __restrict__ wh)
{
    int idx = blockIdx.x * 256 + threadIdx.x;
    if (idx < 512) g_stats[idx] = 0.f;
    if (idx < 64) g_zero[idx] = 0;
    if (idx < 12288) g_whT[idx] = f2bfbits(wh[idx]);       // [oc][192] == OIHW flat
    if (idx < 73728) {
        int tap = idx / 8192, rem = idx & 8191;
        {   int oc = rem >> 6, ic = rem & 63;
            g_wT1[idx] = f2bfbits(w1[(oc * 64 + ic) * 9 + tap]); }
        {   int oc = rem >> 7, ic = rem & 127;
            g_wT2[idx] = f2bfbits(w2[(oc * 128 + ic) * 9 + tap]); }
    }
}

// ---------------------------------------------------------------------------
// transpose x: NCHW f32 -> NHWC bf16
// ---------------------------------------------------------------------------
__global__ __launch_bounds__(256) void transpose_x(const float* __restrict__ x,
                                                   unsigned short* __restrict__ xh)
{
    __shared__ float t[64][65];
    const int tid = threadIdx.x;
    const int bid = blockIdx.x;
    const int n = bid >> 10, pb = bid & 1023;
    const size_t pix0 = (size_t)pb * 64;
    const float* xb = x + ((size_t)n << 22) + pix0;
#pragma unroll
    for (int cb = 0; cb < 4; ++cb) {
        int c = (tid >> 4) + cb * 16;
        int p = (tid & 15) * 4;
        float4 v = *(const float4*)(xb + ((size_t)c << 16) + p);
        t[c][p] = v.x; t[c][p+1] = v.y; t[c][p+2] = v.z; t[c][p+3] = v.w;
    }
    __syncthreads();
    unsigned short* ob = xh + (((size_t)n << 16) + pix0) * 64;
#pragma unroll
    for (int pb2 = 0; pb2 < 2; ++pb2) {
        int p = (tid >> 3) + pb2 * 32;
        int c0 = (tid & 7) * 8;
        v8s r;
#pragma unroll
        for (int i = 0; i < 8; ++i) r[i] = (short)f2bfbits(t[c0 + i][p]);
        *(v8s*)(ob + (size_t)p * 64 + c0) = r;
    }
}

// ---------------------------------------------------------------------------
// conv1: MFMA 3x3, pad=1, NHWC bf16, 64ic -> 128oc. 64-px tiles, all 128 oc.
// 3-deep counted-vmcnt pipeline (R14, best measured).
// Block 512 thr = 8 waves = 4 ocw x 2 pxg; wave 32 oc x 32 px.
// ---------------------------------------------------------------------------
__global__ __launch_bounds__(512, 2) void conv1MFMA(const unsigned short* __restrict__ in,
                                                    unsigned short* __restrict__ outp,
                                                    const int nTiles)
{
    __shared__ __align__(16) unsigned short Xs[3 * CHB + 512];   // 77824 B
    const int tid  = threadIdx.x;
    const int lane = tid & 63;
    const int wv   = tid >> 6;
    const int pg   = (int)blockIdx.x;
    const int NPG  = (int)gridDim.x;

    const int ocw = wv >> 1;              // 0..3 (32-oc group)
    const int wp  = (wv & 1) * 32;        // wave pixel offset
    const int l15 = lane & 15, kg = lane >> 4;

    v8s av[9][2][2];
    {
        const unsigned short* wb =
            g_wT1 + ((size_t)(ocw * 32 + l15)) * 64 + kg * 8;
#pragma unroll
        for (int tap = 0; tap < 9; ++tap)
#pragma unroll
            for (int ics = 0; ics < 2; ++ics)
#pragma unroll
                for (int sub = 0; sub < 2; ++sub)
                    av[tap][ics][sub] =
                        *(const v8s*)(wb + ((size_t)tap * 128 + sub * 16) * 64 + ics * 32);
    }

    auto stage = [&](int s) {
        const int pt   = pg + NPG * s;
        const int n    = pt >> 10;
        const int hrow = (pt >> 2) & 255;
        const int w0   = (pt & 3) * 64;
        unsigned short* buf = Xs + (s % 3) * CHB;
#pragma unroll
        for (int it = 0; it < 4; ++it) {
            const int cb = it * 512 + wv * 64;               // wave-uniform
            unsigned short* dst = (cb >= 1600) ? (Xs + 3 * CHB)
                                               : (buf + (size_t)cb * 8);
            const int chunk = cb + lane;
            int r   = chunk / 528;
            int rem = chunk - r * 528;
            int lc  = rem >> 3, k = rem & 7;
            int gr  = hrow - 1 + r;
            int gc  = w0 - 1 + lc;
            const unsigned short* src;
            if ((chunk < 1584) & ((unsigned)gr < 256u) & ((unsigned)gc < 256u))
                src = in + ((((size_t)n << 16) + ((size_t)gr << 8) + gc) * 64)
                         + ((k ^ (lc & 7)) << 3);
            else
                src = g_zero;
            gll16(src, dst);                                 // always issued: 4/wave
        }
    };

    stage(0);
    stage(1);
    asm volatile("s_waitcnt vmcnt(4)" ::: "memory");   // drain stage(0) (+av)
    __builtin_amdgcn_s_barrier();
    __builtin_amdgcn_sched_barrier(0);

    for (int s = 0; s < nTiles; ++s) {
        if (s + 2 < nTiles) stage(s + 2);                // fly across 2 barriers

        const unsigned short* cur = Xs + (s % 3) * CHB;
        const int pt   = pg + NPG * s;
        const int n    = pt >> 10;
        const int hrow = (pt >> 2) & 255;
        const int w0   = (pt & 3) * 64;
        const size_t pixbase = ((size_t)n << 16) + ((size_t)hrow << 8) + w0;

        v4f acc[2][2];
        {
            v4f z = {0.f, 0.f, 0.f, 0.f};
            acc[0][0] = z; acc[0][1] = z; acc[1][0] = z; acc[1][1] = z;
        }
#pragma unroll
        for (int tap = 0; tap < 9; ++tap) {
            const int dyy = tap / 3, dxx = tap % 3;
            const int lc0 = wp + l15 + dxx;
#pragma unroll
            for (int ics = 0; ics < 2; ++ics) {
                const int off0 = ((dyy * 66 + lc0) * 8 + ((ics * 4 + kg) ^ (lc0 & 7))) * 8;
                v8s b0 = *(const v8s*)(cur + off0);
                v8s b1 = *(const v8s*)(cur + off0 + 16 * 64);   // lc0+16: same (lc&7)
                acc[0][0] = __builtin_amdgcn_mfma_f32_16x16x32_bf16(av[tap][ics][0], b0, acc[0][0], 0, 0, 0);
                acc[1][0] = __builtin_amdgcn_mfma_f32_16x16x32_bf16(av[tap][ics][1], b0, acc[1][0], 0, 0, 0);
                acc[0][1] = __builtin_amdgcn_mfma_f32_16x16x32_bf16(av[tap][ics][0], b1, acc[0][1], 0, 0, 0);
                acc[1][1] = __builtin_amdgcn_mfma_f32_16x16x32_bf16(av[tap][ics][1], b1, acc[1][1], 0, 0, 0);
            }
        }

        if (s + 2 < nTiles) asm volatile("s_waitcnt vmcnt(4)" ::: "memory");
        else                asm volatile("s_waitcnt vmcnt(0)" ::: "memory");

#pragma unroll
        for (int sub = 0; sub < 2; ++sub)
#pragma unroll
            for (int ps = 0; ps < 2; ++ps) {
                const int px  = wp + ps * 16 + l15;
                const int ocb = ocw * 32 + sub * 16 + kg * 4;
                size_t gaddr = (pixbase + px) * 128 + ocb;
                v4f a = acc[sub][ps];
                v4u pk;
#pragma unroll
                for (int r = 0; r < 4; ++r) pk[r] = f2bfbits(a[r]);
                *(v4u*)(outp + gaddr) = pk;
            }

        __builtin_amdgcn_s_barrier();
        __builtin_amdgcn_sched_barrier(0);
    }
}

// ---------------------------------------------------------------------------
// conv2: single-pass MFMA 3x3, 128ic -> 64oc, granule-v1 output.
// 3-deep counted-vmcnt pipeline over (tile, ic-half) steps; static halves.
// Block 512 thr = 8 waves = 4 ocq x 2 pxg; wave 16 oc x 32 px.
// ---------------------------------------------------------------------------
__global__ __launch_bounds__(512, 2) void conv2MFMA(const unsigned short* __restrict__ in,
                                                    unsigned short* __restrict__ outp,
                                                    const int nTiles)
{
    __shared__ __align__(16) unsigned short Xs[3 * CHB + 512];   // 77824 B
    const int tid  = threadIdx.x;
    const int lane = tid & 63;
    const int wv   = tid >> 6;
    const int pg   = (int)blockIdx.x;
    const int NPG  = (int)gridDim.x;

    const int ocq = wv >> 1;              // 0..3 (16-oc group)
    const int wp  = (wv & 1) * 32;
    const int l15 = lane & 15, kg = lane >> 4;

    v8s av[9][4];
    {
        const unsigned short* wb =
            g_wT2 + ((size_t)(ocq * 16 + l15)) * 128 + kg * 8;
#pragma unroll
        for (int tap = 0; tap < 9; ++tap)
#pragma unroll
            for (int ics = 0; ics < 4; ++ics)
                av[tap][ics] = *(const v8s*)(wb + (size_t)tap * 64 * 128 + ics * 32);
    }

    auto stageH = [&](int s) {            // step s: tile s>>1, ic-half s&1
        const int tt    = s >> 1;
        const int icoff = (s & 1) * 64;
        const int pt   = pg + NPG * tt;
        const int n    = pt >> 10;
        const int hrow = (pt >> 2) & 255;
        const int w0   = (pt & 3) * 64;
#pragma unroll
        for (int it = 0; it < 4; ++it) {
            const int cb = it * 512 + wv * 64;
            unsigned short* buf = Xs + (s % 3) * CHB;
            unsigned short* dst = (cb >= 1600) ? (Xs + 3 * CHB)
                                               : (buf + (size_t)cb * 8);
            const int chunk = cb + lane;
            int r   = chunk / 528;
            int rem = chunk - r * 528;
            int lc  = rem >> 3, k = rem & 7;
            int gr  = hrow - 1 + r;
            int gc  = w0 - 1 + lc;
            const unsigned short* src;
            if ((chunk < 1584) & ((unsigned)gr < 256u) & ((unsigned)gc < 256u))
                src = in + ((((size_t)n << 16) + ((size_t)gr << 8) + gc) * 128)
                         + icoff + ((k ^ (lc & 7)) << 3);
            else
                src = g_zero;
            gll16(src, dst);
        }
    };

    const int NS = nTiles * 2;
    stageH(0);
    stageH(1);
    asm volatile("s_waitcnt vmcnt(4)" ::: "memory");
    __builtin_amdgcn_s_barrier();
    __builtin_amdgcn_sched_barrier(0);

    for (int t = 0; t < nTiles; ++t) {
        const int s0 = 2 * t;
        v4f acc[2];
        {
            v4f z = {0.f, 0.f, 0.f, 0.f};
            acc[0] = z; acc[1] = z;
        }

        // ---- even step s0: ic 0..63 from buf[s0%3]
        if (s0 + 2 < NS) stageH(s0 + 2);
        {
            const unsigned short* cur = Xs + (s0 % 3) * CHB;
#pragma unroll
            for (int tap = 0; tap < 9; ++tap) {
                const int dyy = tap / 3, dxx = tap % 3;
                const int lc0 = wp + l15 + dxx;
#pragma unroll
                for (int i2 = 0; i2 < 2; ++i2) {
                    const int off0 = ((dyy * 66 + lc0) * 8 + ((i2 * 4 + kg) ^ (lc0 & 7))) * 8;
                    v8s b0 = *(const v8s*)(cur + off0);
                    v8s b1 = *(const v8s*)(cur + off0 + 16 * 64);
                    acc[0] = __builtin_amdgcn_mfma_f32_16x16x32_bf16(av[tap][i2], b0, acc[0], 0, 0, 0);
                    acc[1] = __builtin_amdgcn_mfma_f32_16x16x32_bf16(av[tap][i2], b1, acc[1], 0, 0, 0);
                }
            }
        }
        if (s0 + 2 < NS) asm volatile("s_waitcnt vmcnt(4)" ::: "memory");
        else             asm volatile("s_waitcnt vmcnt(0)" ::: "memory");
        __builtin_amdgcn_s_barrier();
        __builtin_amdgcn_sched_barrier(0);

        // ---- odd step s0+1: ic 64..127 from buf[(s0+1)%3]
        if (s0 + 3 < NS) stageH(s0 + 3);
        {
            const unsigned short* cur = Xs + ((s0 + 1) % 3) * CHB;
#pragma unroll
            for (int tap = 0; tap < 9; ++tap) {
                const int dyy = tap / 3, dxx = tap % 3;
                const int lc0 = wp + l15 + dxx;
#pragma unroll
                for (int i2 = 0; i2 < 2; ++i2) {
                    const int off0 = ((dyy * 66 + lc0) * 8 + ((i2 * 4 + kg) ^ (lc0 & 7))) * 8;
                    v8s b0 = *(const v8s*)(cur + off0);
                    v8s b1 = *(const v8s*)(cur + off0 + 16 * 64);
                    acc[0] = __builtin_amdgcn_mfma_f32_16x16x32_bf16(av[tap][2 + i2], b0, acc[0], 0, 0, 0);
                    acc[1] = __builtin_amdgcn_mfma_f32_16x16x32_bf16(av[tap][2 + i2], b1, acc[1], 0, 0, 0);
                }
            }
        }
        if (s0 + 3 < NS) asm volatile("s_waitcnt vmcnt(4)" ::: "memory");
        else             asm volatile("s_waitcnt vmcnt(0)" ::: "memory");

        // ---- epilogue: granule-v1 stores for tile t
        {
            const int pt   = pg + NPG * t;
            const int n    = pt >> 10;
            const int hrow = (pt >> 2) & 255;
            const int w0   = (pt & 3) * 64;
            const size_t gb = (size_t)(hrow & 1) * 16777216 + (size_t)n * 2097152
                            + (size_t)(hrow >> 1) * 256;
#pragma unroll
            for (int ps = 0; ps < 2; ++ps) {
                const int px = wp + ps * 16 + l15;
                const int wc = w0 + px;
                const int ocb = ocq * 16 + kg * 4;
                size_t gaddr = gb + (size_t)(wc >> 2) * 32768
                             + (size_t)((wc & 3) * 64 + ocb);
                v4u pk;
#pragma unroll
                for (int r = 0; r < 4; ++r) pk[r] = f2bfbits(acc[ps][r]);
                *(v4u*)(outp + gaddr) = pk;
            }
        }

        __builtin_amdgcn_s_barrier();
        __builtin_amdgcn_sched_barrier(0);
    }
}

// ---------------------------------------------------------------------------
// statsP: per-channel sum/sumsq partials over bf16 [P][C] -> g_part (NO atomics)
// ---------------------------------------------------------------------------
template<int C, int PBASE>
__global__ __launch_bounds__(256) void statsP(const unsigned short* __restrict__ in, int P)
{
    constexpr int G = C / 8;
    constexpr int LG = (G == 16) ? 4 : 3;
    __shared__ float red[256 * 8];
    const int tid = threadIdx.x;
    const int cg = tid & (G - 1);
    float s[8], q[8];
#pragma unroll
    for (int j = 0; j < 8; ++j) { s[j] = 0.f; q[j] = 0.f; }
    const int tot = P * G;
    const int stride = gridDim.x * 256;
    for (int i = blockIdx.x * 256 + tid; i < tot; i += stride) {
        const int p = i >> LG;
        v8s v = *(const v8s*)(in + (size_t)p * C + cg * 8);
#pragma unroll
        for (int j = 0; j < 8; ++j) {
            float f = bfbits2f((unsigned short)v[j]);
            s[j] += f; q[j] = fmaf(f, f, q[j]);
        }
    }
#pragma unroll
    for (int j = 0; j < 8; ++j) red[tid * 8 + j] = s[j];
    __syncthreads();
    for (int st = (256 / G) >> 1; st > 0; st >>= 1) {
        if ((tid >> LG) < st)
#pragma unroll
            for (int j = 0; j < 8; ++j) red[tid * 8 + j] += red[(tid + st * G) * 8 + j];
        __syncthreads();
    }
    if (tid < G)
#pragma unroll
        for (int j = 0; j < 8; ++j)
            g_part[PBASE + blockIdx.x * (2 * C) + 2 * (cg * 8 + j)] = red[tid * 8 + j];
    __syncthreads();
#pragma unroll
    for (int j = 0; j < 8; ++j) red[tid * 8 + j] = q[j];
    __syncthreads();
    for (int st = (256 / G) >> 1; st > 0; st >>= 1) {
        if ((tid >> LG) < st)
#pragma unroll
            for (int j = 0; j < 8; ++j) red[tid * 8 + j] += red[(tid + st * G) * 8 + j];
        __syncthreads();
    }
    if (tid < G)
#pragma unroll
        for (int j = 0; j < 8; ++j)
            g_part[PBASE + blockIdx.x * (2 * C) + 2 * (cg * 8 + j) + 1] = red[tid * 8 + j];
}

// ---------------------------------------------------------------------------
// statsR v2 (PARALLEL): one block per output scalar v; 256 threads stride
// the partials; shfl+LDS reduce; lane 0 writes g_stats[OFF+v].
// ---------------------------------------------------------------------------
template<int NV, int PBASE, int OFF>
__global__ __launch_bounds__(256) void statsR(int nparts)
{
    const int v = (int)blockIdx.x;        // 0..NV-1
    float s = 0.f;
    for (int b = (int)threadIdx.x; b < nparts; b += 256)
        s += g_part[PBASE + b * NV + v];
    s += __shfl_down(s, 32); s += __shfl_down(s, 16);
    s += __shfl_down(s, 8);  s += __shfl_down(s, 4);
    s += __shfl_down(s, 2);  s += __shfl_down(s, 1);
    __shared__ float ls[4];
    if ((threadIdx.x & 63) == 0) ls[threadIdx.x >> 6] = s;
    __syncthreads();
    if (threadIdx.x == 0)
        g_stats[OFF + v] = ls[0] + ls[1] + ls[2] + ls[3];
}

// ---------------------------------------------------------------------------
// BN + mish over NHWC bf16, 8 elems/thread (bn1)
// ---------------------------------------------------------------------------
template<int C, int OFF>
__global__ __launch_bounds__(256) void bnN(const unsigned short* __restrict__ in,
                                           unsigned short* __restrict__ outp,
                                           const float* __restrict__ gam,
                                           const float* __restrict__ bet, int total8)
{
    const int t0 = blockIdx.x * 256 + threadIdx.x;
    const int c0 = (t0 * 8) & (C - 1);
    float sc[8], sh[8];
#pragma unroll
    for (int j = 0; j < 8; ++j) {
        int c = c0 + j;
        float m  = g_stats[OFF + 2 * c] * INV_CNT;
        float va = fmaf(g_stats[OFF + 2 * c + 1], INV_CNT, -m * m);
        sc[j] = rsqrtf(va + EPS_) * gam[c];
        sh[j] = fmaf(-m, sc[j], bet[c]);
    }
    const int stride = gridDim.x * 256;
    for (int i = t0; i < total8; i += stride) {
        v8s v = *(const v8s*)(in + (size_t)i * 8);
        v8s o;
#pragma unroll
        for (int j = 0; j < 8; ++j)
            o[j] = (short)f2bfbits(mishf(fmaf(bfbits2f((unsigned short)v[j]), sc[j], sh[j])));
        *(v8s*)(outp + (size_t)i * 8) = o;
    }
}

// ---------------------------------------------------------------------------
// haarFused v3 + partial-store statsH (no atomics): bn2+mish + bf16 residual
// (xh) -> Haar -> cA + MFMA 1x1 (192->64) -> convh raw + statsH partials.
// c2 read from d_out in granule-v1; block-private aliasing as before.
// Block: 512 thr, one lowres row (128 px). Grid 1024 = 8 n x 128 rows.
// ---------------------------------------------------------------------------
__global__ __launch_bounds__(512) void haarFused(const unsigned short* c2,
                                                 const unsigned short* __restrict__ xh,
                                                 const float* __restrict__ g2,
                                                 const float* __restrict__ be2,
                                                 float* out_low,
                                                 float* convh)
{
    __shared__ __align__(16) unsigned short Bs[128 * 192];   // 49152 B; Cf overlays
    const int tid = threadIdx.x, lane = tid & 63;
    const int n = blockIdx.x >> 7, row = blockIdx.x & 127;

    const int wv = tid >> 6;
    const int ocw = wv >> 2, wp = (wv & 3) * 32;
    const int l15 = lane & 15, kg = lane >> 4;

    // ---- phase A: loads + bn2+mish+residual + haar (NO global stores yet)
    const int px = tid >> 2, cg = tid & 3;
    float low[16];
    v8s Hb[2], Vb[2], Db[2];
    {
        float sc[16], sh[16];
#pragma unroll
        for (int j = 0; j < 16; ++j) {
            int c = cg * 16 + j;
            float m  = g_stats[256 + 2 * c] * INV_CNT;
            float va = fmaf(g_stats[256 + 2 * c + 1], INV_CNT, -m * m);
            sc[j] = rsqrtf(va + EPS_) * g2[c];
            sh[j] = fmaf(-m, sc[j], be2[c]);
        }
        // c2 granule-v1 reads: pixel (2row+i, 2px+m), ch cg*16 + [0,16)
        const size_t cbase = (size_t)n * 2097152 + (size_t)(px >> 1) * 32768
                           + (size_t)row * 256 + (px & 1) * 128 + cg * 16;
        const size_t xbase = ((size_t)n * 65536 + (size_t)(2 * row) * 256 + 2 * px) * 64 + cg * 16;
        v8s cv[2][2][2], xv[2][2][2];
#pragma unroll
        for (int i = 0; i < 2; ++i)
#pragma unroll
            for (int m = 0; m < 2; ++m) {
                const unsigned short* cp = c2 + cbase + (size_t)i * 16777216 + m * 64;
                cv[i][m][0] = *(const v8s*)cp;
                cv[i][m][1] = *(const v8s*)(cp + 8);
                const unsigned short* xp = xh + xbase + i * 16384 + m * 64;
                xv[i][m][0] = *(const v8s*)xp;
                xv[i][m][1] = *(const v8s*)(xp + 8);
            }
#pragma unroll
        for (int jj = 0; jj < 2; ++jj)
#pragma unroll
            for (int j = 0; j < 8; ++j) {
                const int jc = jj * 8 + j;
                float y00 = mishf(fmaf(bfbits2f((unsigned short)cv[0][0][jj][j]), sc[jc], sh[jc]))
                          + bfbits2f((unsigned short)xv[0][0][jj][j]);
                float y01 = mishf(fmaf(bfbits2f((unsigned short)cv[0][1][jj][j]), sc[jc], sh[jc]))
                          + bfbits2f((unsigned short)xv[0][1][jj][j]);
                float y10 = mishf(fmaf(bfbits2f((unsigned short)cv[1][0][jj][j]), sc[jc], sh[jc]))
                          + bfbits2f((unsigned short)xv[1][0][jj][j]);
                float y11 = mishf(fmaf(bfbits2f((unsigned short)cv[1][1][jj][j]), sc[jc], sh[jc]))
                          + bfbits2f((unsigned short)xv[1][1][jj][j]);
                low[jc] = 0.5f * (y00 + y01 + y10 + y11);
                Hb[jj][j] = (short)f2bfbits(0.5f * (y00 + y01 - y10 - y11));
                Vb[jj][j] = (short)f2bfbits(0.5f * (y00 - y01 + y10 - y11));
                Db[jj][j] = (short)f2bfbits(0.5f * (y00 - y01 - y10 + y11));
            }
        unsigned short* bp = Bs + px * 192;
        const int sx = px & 7;
#pragma unroll
        for (int jj = 0; jj < 2; ++jj) {
            *(v8s*)(bp + (((cg * 2 + jj) ^ sx) << 3))      = Hb[jj];
            *(v8s*)(bp + (((8 + cg * 2 + jj) ^ sx) << 3))  = Vb[jj];
            *(v8s*)(bp + (((16 + cg * 2 + jj) ^ sx) << 3)) = Db[jj];
        }
    }
    __syncthreads();   // all c2 reads consumed block-wide; Bs ready

    // ---- out_low stores (clobber this block's own r=0 granules — now safe)
#pragma unroll
    for (int j = 0; j < 16; ++j) {
        const int c = cg * 16 + j;
        out_low[((size_t)(n * 64 + c) << 14) + row * 128 + px] = low[j];
    }

    // ---- A fragments (whT, L2-hot)
    v8s av2[6][2];
    {
        const unsigned short* wb = g_whT + (size_t)(ocw * 32 + l15) * 192 + kg * 8;
#pragma unroll
        for (int s = 0; s < 6; ++s)
#pragma unroll
            for (int sub = 0; sub < 2; ++sub)
                av2[s][sub] = *(const v8s*)(wb + (size_t)sub * 16 * 192 + s * 32);
    }

    // ---- phase B: MFMA, K=192 (6 steps)
    v4f acc[2][2];
    {
        v4f z = {0.f, 0.f, 0.f, 0.f};
        acc[0][0] = z; acc[0][1] = z; acc[1][0] = z; acc[1][1] = z;
    }
    {
        const int pix0 = wp + l15;
        const unsigned short* bbase = Bs + pix0 * 192;
        const int sx0 = pix0 & 7;
#pragma unroll
        for (int s = 0; s < 6; ++s) {
            const int ck = s * 4 + kg;
            v8s b0 = *(const v8s*)(bbase + ((ck ^ sx0) << 3));
            v8s b1 = *(const v8s*)(bbase + 16 * 192 + ((ck ^ sx0) << 3));
            acc[0][0] = __builtin_amdgcn_mfma_f32_16x16x32_bf16(av2[s][0], b0, acc[0][0], 0, 0, 0);
            acc[1][0] = __builtin_amdgcn_mfma_f32_16x16x32_bf16(av2[s][1], b0, acc[1][0], 0, 0, 0);
            acc[0][1] = __builtin_amdgcn_mfma_f32_16x16x32_bf16(av2[s][0], b1, acc[0][1], 0, 0, 0);
            acc[1][1] = __builtin_amdgcn_mfma_f32_16x16x32_bf16(av2[s][1], b1, acc[1][1], 0, 0, 0);
        }
    }

    // ---- phase C: Cf [64 oc][130 px] f32 (overlay Bs) -> coalesced NCHW + stats
    __syncthreads();
    float* Cf = (float*)Bs;
#pragma unroll
    for (int sub = 0; sub < 2; ++sub)
#pragma unroll
        for (int ps = 0; ps < 2; ++ps) {
            const int pxe = wp + ps * 16 + l15;
            const int ocb = ocw * 32 + sub * 16 + kg * 4;
#pragma unroll
            for (int r = 0; r < 4; ++r)
                Cf[(ocb + r) * 130 + pxe] = acc[sub][ps][r];
        }
    __syncthreads();
    {
        const int oc = tid >> 3, seg = tid & 7;
        float vals[16];
        float S = 0.f, Q = 0.f;
#pragma unroll
        for (int i = 0; i < 16; ++i) {
            float f = Cf[oc * 130 + seg * 16 + i];
            vals[i] = f; S += f; Q = fmaf(f, f, Q);
        }
        float* gp = convh + ((size_t)(n * 64 + oc) << 14) + row * 128 + seg * 16;
#pragma unroll
        for (int i4 = 0; i4 < 4; ++i4) {
            float4 t4;
            t4.x = vals[i4*4]; t4.y = vals[i4*4+1]; t4.z = vals[i4*4+2]; t4.w = vals[i4*4+3];
            *(float4*)(gp + i4 * 4) = t4;
        }
        S += __shfl_down(S, 4); Q += __shfl_down(Q, 4);
        S += __shfl_down(S, 2); Q += __shfl_down(Q, 2);
        S += __shfl_down(S, 1); Q += __shfl_down(Q, 1);
        if (seg == 0) {
            g_part[PBH + (size_t)blockIdx.x * 128 + 2 * oc]     = S;
            g_part[PBH + (size_t)blockIdx.x * 128 + 2 * oc + 1] = Q;
        }
    }
}

// ---------------------------------------------------------------------------
// final BN+mish on convh (NCHW f32), in place
// ---------------------------------------------------------------------------
__global__ __launch_bounds__(256) void bnF(const float* __restrict__ in,
                                           float* __restrict__ outp, int stOff,
                                           const float* __restrict__ gam,
                                           const float* __restrict__ bet,
                                           int Cmask, int logHW, float invCnt, int total4)
{
    int t = blockIdx.x * 256 + threadIdx.x;
    if (t >= total4) return;
    int idx = t << 2;
    int c = (idx >> logHW) & Cmask;
    float mean = g_stats[stOff + 2 * c] * invCnt;
    float var = fmaf(g_stats[stOff + 2 * c + 1], invCnt, -mean * mean);
    float scale = rsqrtf(var + EPS_) * gam[c];
    float shift = fmaf(-mean, scale, bet[c]);
    float4 v = *(const float4*)(in + idx);
    v.x = mishf(fmaf(v.x, scale, shift));
    v.y = mishf(fmaf(v.y, scale, shift));
    v.z = mishf(fmaf(v.z, scale, shift));
    v.w = mishf(fmaf(v.w, scale, shift));
    *(float4*)(outp + idx) = v;
}

// ---------------------------------------------------------------------------
extern "C" void kernel_launch(void* const* d_in, const int* in_sizes, int n_in,
                              void* d_out, int out_size, void* d_ws, size_t ws_size,
                              hipStream_t stream)
{
    (void)in_sizes; (void)n_in; (void)out_size; (void)ws_size;

    const float* x   = (const float*)d_in[0];
    const float* w1  = (const float*)d_in[1];
    const float* g1  = (const float*)d_in[3];
    const float* be1 = (const float*)d_in[4];
    const float* w2  = (const float*)d_in[5];
    const float* g2  = (const float*)d_in[7];
    const float* be2 = (const float*)d_in[8];
    const float* wh  = (const float*)d_in[9];
    const float* gh  = (const float*)d_in[11];
    const float* beh = (const float*)d_in[12];
    // biases b1,b2,bh are mathematically absorbed by the following BatchNorms.

    char* ws = (char*)d_ws;
    unsigned short* xh = (unsigned short*)ws;                 // x NHWC bf16 (stays live)
    unsigned short* h1 = (unsigned short*)(ws + 67108864);    // conv1 out NHWC bf16
    unsigned short* c2 = (unsigned short*)d_out;              // conv2 raw bf16, granule-v1 in d_out
    float* out_low = (float*)d_out;
    float* convh   = (float*)d_out + 8388608;

    prep<<<288, 256, 0, stream>>>(w1, w2, wh);
    transpose_x<<<8192, 256, 0, stream>>>(x, xh);

    // conv1: xh -> h1 raw (64-px tiles, 128 oc/block, 3-deep counted-vmcnt)
    conv1MFMA<<<1024, 512, 0, stream>>>(xh, h1, 8);
    // stats1: partial reduce (no atomics) + parallel final reduce
    statsP<128, PB1><<<1024, 256, 0, stream>>>(h1, 524288);
    statsR<256, PB1, 0><<<256, 256, 0, stream>>>(1024);
    bnN<128, 0><<<1024, 256, 0, stream>>>(h1, h1, g1, be1, 8388608);
    // conv2 single-pass: h1 -> c2 (granule-v1; 3-deep counted-vmcnt)
    conv2MFMA<<<2048, 512, 0, stream>>>(h1, c2, 4);
    // stats2: partial reduce + parallel final reduce
    statsP<64, PB2><<<512, 256, 0, stream>>>(c2, 524288);
    statsR<128, PB2, 256><<<128, 256, 0, stream>>>(512);
    // bn2+mish+residual(xh) + haar + 1x1 MFMA (+statsH partials)
    haarFused<<<1024, 512, 0, stream>>>(c2, xh, g2, be2, out_low, convh);
    statsR<128, PBH, 384><<<128, 256, 0, stream>>>(1024);
    // final bn+mish on convh
    bnF<<<8192, 256, 0, stream>>>(convh, convh, 384, gh, beh, 63, 14, 1.f / 131072.f, 2097152);
}

// Round 19
// 443.395 us; speedup vs baseline: 3.8396x; 1.0008x over previous
//
#include <hip/hip_runtime.h>
#include <hip/hip_bf16.h>

#define DEV static __device__ __forceinline__

typedef short v8s __attribute__((ext_vector_type(8)));
typedef float v4f __attribute__((ext_vector_type(4)));
typedef unsigned short v4u __attribute__((ext_vector_type(4)));

constexpr int N_ = 8;
constexpr float EPS_ = 1e-5f;
constexpr float INV_CNT = 1.f / 524288.f;   // 1/(8*256*256)
constexpr int CHB = 12800;                  // ushorts per staging buffer (25600 B)

// g_part layout: stats1 partials [0, 262144) = 1024 blk x 256
//                stats2 partials [262144, 327680) = 512 blk x 128
//                statsH partials [327680, 458752) = 1024 blk x 128
constexpr int PB1 = 0;
constexpr int PB2 = 262144;
constexpr int PBH = 327680;

// c2 granule layout v1 (block-private aliasing with d_out, full-row haar blocks):
//   element (n, hr, wc, ch), r=hr&1, row=hr>>1  ->  ushort offset
//   r*16777216 + n*2097152 + (wc>>2)*32768 + row*256 + (wc&3)*64 + ch

// device-global scratch
__device__ __align__(16) unsigned short g_wT1[9*128*64];   // [tap][oc][ic] bf16
__device__ __align__(16) unsigned short g_wT2[9*64*128];
__device__ __align__(16) unsigned short g_whT[64*192];     // [oc][k] bf16
__device__ __align__(16) float g_stats[512];               // s1[0:256) s2[256:384) sH[384:512)
__device__ __align__(16) float g_part[458752];             // per-block stats partials
__device__ __align__(16) unsigned short g_zero[64];

DEV float bfbits2f(unsigned short u) { return __uint_as_float(((unsigned)u) << 16); }
DEV unsigned short f2bfbits(float f) {
    __hip_bfloat16 h = __float2bfloat16(f);
    unsigned short b;
    __builtin_memcpy(&b, &h, 2);
    return b;
}

DEV float mishf(float v) {
    // mish(v) = v * t(t+2)/(t(t+2)+2), t = e^v
    float t = __expf(fminf(v, 30.f));
    float num = fmaf(t, t, 2.f * t);
    return v * num * __builtin_amdgcn_rcpf(num + 2.f);
}

DEV void gll16(const unsigned short* g, unsigned short* l) {
    __builtin_amdgcn_global_load_lds(
        (const __attribute__((address_space(1))) unsigned int*)g,
        (__attribute__((address_space(3))) unsigned int*)l,
        16, 0, 0);
}

// ---------------------------------------------------------------------------
// prep: weight reorders (bf16) + zero stats + zero page
// ---------------------------------------------------------------------------
__global__ __launch_bounds__(256) void prep(const float* __restrict__ w1,
                                            const float* __restrict__ w2,
                                            const float* __restrict__ wh)
{
    int idx = blockIdx.x * 256 + threadIdx.x;
    if (idx < 512) g_stats[idx] = 0.f;
    if (idx < 64) g_zero[idx] = 0;
    if (idx < 12288) g_whT[idx] = f2bfbits(wh[idx]);       // [oc][192] == OIHW flat
    if (idx < 73728) {
        int tap = idx / 8192, rem = idx & 8191;
        {   int oc = rem >> 6, ic = rem & 63;
            g_wT1[idx] = f2bfbits(w1[(oc * 64 + ic) * 9 + tap]); }
        {   int oc = rem >> 7, ic = rem & 127;
            g_wT2[idx] = f2bfbits(w2[(oc * 128 + ic) * 9 + tap]); }
    }
}

// ---------------------------------------------------------------------------
// transpose x: NCHW f32 -> NHWC bf16
// ---------------------------------------------------------------------------
__global__ __launch_bounds__(256) void transpose_x(const float* __restrict__ x,
                                                   unsigned short* __restrict__ xh)
{
    __shared__ float t[64][65];
    const int tid = threadIdx.x;
    const int bid = blockIdx.x;
    const int n = bid >> 10, pb = bid & 1023;
    const size_t pix0 = (size_t)pb * 64;
    const float* xb = x + ((size_t)n << 22) + pix0;
#pragma unroll
    for (int cb = 0; cb < 4; ++cb) {
        int c = (tid >> 4) + cb * 16;
        int p = (tid & 15) * 4;
        float4 v = *(const float4*)(xb + ((size_t)c << 16) + p);
        t[c][p] = v.x; t[c][p+1] = v.y; t[c][p+2] = v.z; t[c][p+3] = v.w;
    }
    __syncthreads();
    unsigned short* ob = xh + (((size_t)n << 16) + pix0) * 64;
#pragma unroll
    for (int pb2 = 0; pb2 < 2; ++pb2) {
        int p = (tid >> 3) + pb2 * 32;
        int c0 = (tid & 7) * 8;
        v8s r;
#pragma unroll
        for (int i = 0; i < 8; ++i) r[i] = (short)f2bfbits(t[c0 + i][p]);
        *(v8s*)(ob + (size_t)p * 64 + c0) = r;
    }
}

// ---------------------------------------------------------------------------
// conv1: MFMA 3x3, pad=1, NHWC bf16, 64ic -> 128oc. 64-px tiles, all 128 oc.
// 3-deep counted-vmcnt pipeline (R14, best measured).
// Block 512 thr = 8 waves = 4 ocw x 2 pxg; wave 32 oc x 32 px.
// ---------------------------------------------------------------------------
__global__ __launch_bounds__(512, 2) void conv1MFMA(const unsigned short* __restrict__ in,
                                                    unsigned short* __restrict__ outp,
                                                    const int nTiles)
{
    __shared__ __align__(16) unsigned short Xs[3 * CHB + 512];   // 77824 B
    const int tid  = threadIdx.x;
    const int lane = tid & 63;
    const int wv   = tid >> 6;
    const int pg   = (int)blockIdx.x;
    const int NPG  = (int)gridDim.x;

    const int ocw = wv >> 1;              // 0..3 (32-oc group)
    const int wp  = (wv & 1) * 32;        // wave pixel offset
    const int l15 = lane & 15, kg = lane >> 4;

    v8s av[9][2][2];
    {
        const unsigned short* wb =
            g_wT1 + ((size_t)(ocw * 32 + l15)) * 64 + kg * 8;
#pragma unroll
        for (int tap = 0; tap < 9; ++tap)
#pragma unroll
            for (int ics = 0; ics < 2; ++ics)
#pragma unroll
                for (int sub = 0; sub < 2; ++sub)
                    av[tap][ics][sub] =
                        *(const v8s*)(wb + ((size_t)tap * 128 + sub * 16) * 64 + ics * 32);
    }

    auto stage = [&](int s) {
        const int pt   = pg + NPG * s;
        const int n    = pt >> 10;
        const int hrow = (pt >> 2) & 255;
        const int w0   = (pt & 3) * 64;
        unsigned short* buf = Xs + (s % 3) * CHB;
#pragma unroll
        for (int it = 0; it < 4; ++it) {
            const int cb = it * 512 + wv * 64;               // wave-uniform
            unsigned short* dst = (cb >= 1600) ? (Xs + 3 * CHB)
                                               : (buf + (size_t)cb * 8);
            const int chunk = cb + lane;
            int r   = chunk / 528;
            int rem = chunk - r * 528;
            int lc  = rem >> 3, k = rem & 7;
            int gr  = hrow - 1 + r;
            int gc  = w0 - 1 + lc;
            const unsigned short* src;
            if ((chunk < 1584) & ((unsigned)gr < 256u) & ((unsigned)gc < 256u))
                src = in + ((((size_t)n << 16) + ((size_t)gr << 8) + gc) * 64)
                         + ((k ^ (lc & 7)) << 3);
            else
                src = g_zero;
            gll16(src, dst);                                 // always issued: 4/wave
        }
    };

    stage(0);
    stage(1);
    asm volatile("s_waitcnt vmcnt(4)" ::: "memory");   // drain stage(0) (+av)
    __builtin_amdgcn_s_barrier();
    __builtin_amdgcn_sched_barrier(0);

    for (int s = 0; s < nTiles; ++s) {
        if (s + 2 < nTiles) stage(s + 2);                // fly across 2 barriers

        const unsigned short* cur = Xs + (s % 3) * CHB;
        const int pt   = pg + NPG * s;
        const int n    = pt >> 10;
        const int hrow = (pt >> 2) & 255;
        const int w0   = (pt & 3) * 64;
        const size_t pixbase = ((size_t)n << 16) + ((size_t)hrow << 8) + w0;

        v4f acc[2][2];
        {
            v4f z = {0.f, 0.f, 0.f, 0.f};
            acc[0][0] = z; acc[0][1] = z; acc[1][0] = z; acc[1][1] = z;
        }
#pragma unroll
        for (int tap = 0; tap < 9; ++tap) {
            const int dyy = tap / 3, dxx = tap % 3;
            const int lc0 = wp + l15 + dxx;
#pragma unroll
            for (int ics = 0; ics < 2; ++ics) {
                const int off0 = ((dyy * 66 + lc0) * 8 + ((ics * 4 + kg) ^ (lc0 & 7))) * 8;
                v8s b0 = *(const v8s*)(cur + off0);
                v8s b1 = *(const v8s*)(cur + off0 + 16 * 64);   // lc0+16: same (lc&7)
                acc[0][0] = __builtin_amdgcn_mfma_f32_16x16x32_bf16(av[tap][ics][0], b0, acc[0][0], 0, 0, 0);
                acc[1][0] = __builtin_amdgcn_mfma_f32_16x16x32_bf16(av[tap][ics][1], b0, acc[1][0], 0, 0, 0);
                acc[0][1] = __builtin_amdgcn_mfma_f32_16x16x32_bf16(av[tap][ics][0], b1, acc[0][1], 0, 0, 0);
                acc[1][1] = __builtin_amdgcn_mfma_f32_16x16x32_bf16(av[tap][ics][1], b1, acc[1][1], 0, 0, 0);
            }
        }

        if (s + 2 < nTiles) asm volatile("s_waitcnt vmcnt(4)" ::: "memory");
        else                asm volatile("s_waitcnt vmcnt(0)" ::: "memory");

#pragma unroll
        for (int sub = 0; sub < 2; ++sub)
#pragma unroll
            for (int ps = 0; ps < 2; ++ps) {
                const int px  = wp + ps * 16 + l15;
                const int ocb = ocw * 32 + sub * 16 + kg * 4;
                size_t gaddr = (pixbase + px) * 128 + ocb;
                v4f a = acc[sub][ps];
                v4u pk;
#pragma unroll
                for (int r = 0; r < 4; ++r) pk[r] = f2bfbits(a[r]);
                *(v4u*)(outp + gaddr) = pk;
            }

        __builtin_amdgcn_s_barrier();
        __builtin_amdgcn_sched_barrier(0);
    }
}

// ---------------------------------------------------------------------------
// conv2: single-pass MFMA 3x3, 128ic -> 64oc, granule-v1 output.
// 3-deep counted-vmcnt pipeline over (tile, ic-half) steps; static halves.
// Block 512 thr = 8 waves = 4 ocq x 2 pxg; wave 16 oc x 32 px.
// ---------------------------------------------------------------------------
__global__ __launch_bounds__(512, 2) void conv2MFMA(const unsigned short* __restrict__ in,
                                                    unsigned short* __restrict__ outp,
                                                    const int nTiles)
{
    __shared__ __align__(16) unsigned short Xs[3 * CHB + 512];   // 77824 B
    const int tid  = threadIdx.x;
    const int lane = tid & 63;
    const int wv   = tid >> 6;
    const int pg   = (int)blockIdx.x;
    const int NPG  = (int)gridDim.x;

    const int ocq = wv >> 1;              // 0..3 (16-oc group)
    const int wp  = (wv & 1) * 32;
    const int l15 = lane & 15, kg = lane >> 4;

    v8s av[9][4];
    {
        const unsigned short* wb =
            g_wT2 + ((size_t)(ocq * 16 + l15)) * 128 + kg * 8;
#pragma unroll
        for (int tap = 0; tap < 9; ++tap)
#pragma unroll
            for (int ics = 0; ics < 4; ++ics)
                av[tap][ics] = *(const v8s*)(wb + (size_t)tap * 64 * 128 + ics * 32);
    }

    auto stageH = [&](int s) {            // step s: tile s>>1, ic-half s&1
        const int tt    = s >> 1;
        const int icoff = (s & 1) * 64;
        const int pt   = pg + NPG * tt;
        const int n    = pt >> 10;
        const int hrow = (pt >> 2) & 255;
        const int w0   = (pt & 3) * 64;
#pragma unroll
        for (int it = 0; it < 4; ++it) {
            const int cb = it * 512 + wv * 64;
            unsigned short* buf = Xs + (s % 3) * CHB;
            unsigned short* dst = (cb >= 1600) ? (Xs + 3 * CHB)
                                               : (buf + (size_t)cb * 8);
            const int chunk = cb + lane;
            int r   = chunk / 528;
            int rem = chunk - r * 528;
            int lc  = rem >> 3, k = rem & 7;
            int gr  = hrow - 1 + r;
            int gc  = w0 - 1 + lc;
            const unsigned short* src;
            if ((chunk < 1584) & ((unsigned)gr < 256u) & ((unsigned)gc < 256u))
                src = in + ((((size_t)n << 16) + ((size_t)gr << 8) + gc) * 128)
                         + icoff + ((k ^ (lc & 7)) << 3);
            else
                src = g_zero;
            gll16(src, dst);
        }
    };

    const int NS = nTiles * 2;
    stageH(0);
    stageH(1);
    asm volatile("s_waitcnt vmcnt(4)" ::: "memory");
    __builtin_amdgcn_s_barrier();
    __builtin_amdgcn_sched_barrier(0);

    for (int t = 0; t < nTiles; ++t) {
        const int s0 = 2 * t;
        v4f acc[2];
        {
            v4f z = {0.f, 0.f, 0.f, 0.f};
            acc[0] = z; acc[1] = z;
        }

        // ---- even step s0: ic 0..63 from buf[s0%3]
        if (s0 + 2 < NS) stageH(s0 + 2);
        {
            const unsigned short* cur = Xs + (s0 % 3) * CHB;
#pragma unroll
            for (int tap = 0; tap < 9; ++tap) {
                const int dyy = tap / 3, dxx = tap % 3;
                const int lc0 = wp + l15 + dxx;
#pragma unroll
                for (int i2 = 0; i2 < 2; ++i2) {
                    const int off0 = ((dyy * 66 + lc0) * 8 + ((i2 * 4 + kg) ^ (lc0 & 7))) * 8;
                    v8s b0 = *(const v8s*)(cur + off0);
                    v8s b1 = *(const v8s*)(cur + off0 + 16 * 64);
                    acc[0] = __builtin_amdgcn_mfma_f32_16x16x32_bf16(av[tap][i2], b0, acc[0], 0, 0, 0);
                    acc[1] = __builtin_amdgcn_mfma_f32_16x16x32_bf16(av[tap][i2], b1, acc[1], 0, 0, 0);
                }
            }
        }
        if (s0 + 2 < NS) asm volatile("s_waitcnt vmcnt(4)" ::: "memory");
        else             asm volatile("s_waitcnt vmcnt(0)" ::: "memory");
        __builtin_amdgcn_s_barrier();
        __builtin_amdgcn_sched_barrier(0);

        // ---- odd step s0+1: ic 64..127 from buf[(s0+1)%3]
        if (s0 + 3 < NS) stageH(s0 + 3);
        {
            const unsigned short* cur = Xs + ((s0 + 1) % 3) * CHB;
#pragma unroll
            for (int tap = 0; tap < 9; ++tap) {
                const int dyy = tap / 3, dxx = tap % 3;
                const int lc0 = wp + l15 + dxx;
#pragma unroll
                for (int i2 = 0; i2 < 2; ++i2) {
                    const int off0 = ((dyy * 66 + lc0) * 8 + ((i2 * 4 + kg) ^ (lc0 & 7))) * 8;
                    v8s b0 = *(const v8s*)(cur + off0);
                    v8s b1 = *(const v8s*)(cur + off0 + 16 * 64);
                    acc[0] = __builtin_amdgcn_mfma_f32_16x16x32_bf16(av[tap][2 + i2], b0, acc[0], 0, 0, 0);
                    acc[1] = __builtin_amdgcn_mfma_f32_16x16x32_bf16(av[tap][2 + i2], b1, acc[1], 0, 0, 0);
                }
            }
        }
        if (s0 + 3 < NS) asm volatile("s_waitcnt vmcnt(4)" ::: "memory");
        else             asm volatile("s_waitcnt vmcnt(0)" ::: "memory");

        // ---- epilogue: granule-v1 stores for tile t
        {
            const int pt   = pg + NPG * t;
            const int n    = pt >> 10;
            const int hrow = (pt >> 2) & 255;
            const int w0   = (pt & 3) * 64;
            const size_t gb = (size_t)(hrow & 1) * 16777216 + (size_t)n * 2097152
                            + (size_t)(hrow >> 1) * 256;
#pragma unroll
            for (int ps = 0; ps < 2; ++ps) {
                const int px = wp + ps * 16 + l15;
                const int wc = w0 + px;
                const int ocb = ocq * 16 + kg * 4;
                size_t gaddr = gb + (size_t)(wc >> 2) * 32768
                             + (size_t)((wc & 3) * 64 + ocb);
                v4u pk;
#pragma unroll
                for (int r = 0; r < 4; ++r) pk[r] = f2bfbits(acc[ps][r]);
                *(v4u*)(outp + gaddr) = pk;
            }
        }

        __builtin_amdgcn_s_barrier();
        __builtin_amdgcn_sched_barrier(0);
    }
}

// ---------------------------------------------------------------------------
// statsP: per-channel sum/sumsq partials over bf16 [P][C] -> g_part (NO atomics)
// ---------------------------------------------------------------------------
template<int C, int PBASE>
__global__ __launch_bounds__(256) void statsP(const unsigned short* __restrict__ in, int P)
{
    constexpr int G = C / 8;
    constexpr int LG = (G == 16) ? 4 : 3;
    __shared__ float red[256 * 8];
    const int tid = threadIdx.x;
    const int cg = tid & (G - 1);
    float s[8], q[8];
#pragma unroll
    for (int j = 0; j < 8; ++j) { s[j] = 0.f; q[j] = 0.f; }
    const int tot = P * G;
    const int stride = gridDim.x * 256;
    for (int i = blockIdx.x * 256 + tid; i < tot; i += stride) {
        const int p = i >> LG;
        v8s v = *(const v8s*)(in + (size_t)p * C + cg * 8);
#pragma unroll
        for (int j = 0; j < 8; ++j) {
            float f = bfbits2f((unsigned short)v[j]);
            s[j] += f; q[j] = fmaf(f, f, q[j]);
        }
    }
#pragma unroll
    for (int j = 0; j < 8; ++j) red[tid * 8 + j] = s[j];
    __syncthreads();
    for (int st = (256 / G) >> 1; st > 0; st >>= 1) {
        if ((tid >> LG) < st)
#pragma unroll
            for (int j = 0; j < 8; ++j) red[tid * 8 + j] += red[(tid + st * G) * 8 + j];
        __syncthreads();
    }
    if (tid < G)
#pragma unroll
        for (int j = 0; j < 8; ++j)
            g_part[PBASE + blockIdx.x * (2 * C) + 2 * (cg * 8 + j)] = red[tid * 8 + j];
    __syncthreads();
#pragma unroll
    for (int j = 0; j < 8; ++j) red[tid * 8 + j] = q[j];
    __syncthreads();
    for (int st = (256 / G) >> 1; st > 0; st >>= 1) {
        if ((tid >> LG) < st)
#pragma unroll
            for (int j = 0; j < 8; ++j) red[tid * 8 + j] += red[(tid + st * G) * 8 + j];
        __syncthreads();
    }
    if (tid < G)
#pragma unroll
        for (int j = 0; j < 8; ++j)
            g_part[PBASE + blockIdx.x * (2 * C) + 2 * (cg * 8 + j) + 1] = red[tid * 8 + j];
}

// ---------------------------------------------------------------------------
// statsR v2 (PARALLEL): one block per output scalar v; 256 threads stride
// the partials; shfl+LDS reduce; lane 0 writes g_stats[OFF+v].
// ---------------------------------------------------------------------------
template<int NV, int PBASE, int OFF>
__global__ __launch_bounds__(256) void statsR(int nparts)
{
    const int v = (int)blockIdx.x;        // 0..NV-1
    float s = 0.f;
    for (int b = (int)threadIdx.x; b < nparts; b += 256)
        s += g_part[PBASE + b * NV + v];
    s += __shfl_down(s, 32); s += __shfl_down(s, 16);
    s += __shfl_down(s, 8);  s += __shfl_down(s, 4);
    s += __shfl_down(s, 2);  s += __shfl_down(s, 1);
    __shared__ float ls[4];
    if ((threadIdx.x & 63) == 0) ls[threadIdx.x >> 6] = s;
    __syncthreads();
    if (threadIdx.x == 0)
        g_stats[OFF + v] = ls[0] + ls[1] + ls[2] + ls[3];
}

// ---------------------------------------------------------------------------
// BN + mish over NHWC bf16, 8 elems/thread (bn1)
// ---------------------------------------------------------------------------
template<int C, int OFF>
__global__ __launch_bounds__(256) void bnN(const unsigned short* __restrict__ in,
                                           unsigned short* __restrict__ outp,
                                           const float* __restrict__ gam,
                                           const float* __restrict__ bet, int total8)
{
    const int t0 = blockIdx.x * 256 + threadIdx.x;
    const int c0 = (t0 * 8) & (C - 1);
    float sc[8], sh[8];
#pragma unroll
    for (int j = 0; j < 8; ++j) {
        int c = c0 + j;
        float m  = g_stats[OFF + 2 * c] * INV_CNT;
        float va = fmaf(g_stats[OFF + 2 * c + 1], INV_CNT, -m * m);
        sc[j] = rsqrtf(va + EPS_) * gam[c];
        sh[j] = fmaf(-m, sc[j], bet[c]);
    }
    const int stride = gridDim.x * 256;
    for (int i = t0; i < total8; i += stride) {
        v8s v = *(const v8s*)(in + (size_t)i * 8);
        v8s o;
#pragma unroll
        for (int j = 0; j < 8; ++j)
            o[j] = (short)f2bfbits(mishf(fmaf(bfbits2f((unsigned short)v[j]), sc[j], sh[j])));
        *(v8s*)(outp + (size_t)i * 8) = o;
    }
}

// ---------------------------------------------------------------------------
// haarFused v3 + partial-store statsH (no atomics): bn2+mish + bf16 residual
// (xh) -> Haar -> cA + MFMA 1x1 (192->64) -> convh raw + statsH partials.
// c2 read from d_out in granule-v1; block-private aliasing as before.
// Block: 512 thr, one lowres row (128 px). Grid 1024 = 8 n x 128 rows.
// ---------------------------------------------------------------------------
__global__ __launch_bounds__(512) void haarFused(const unsigned short* c2,
                                                 const unsigned short* __restrict__ xh,
                                                 const float* __restrict__ g2,
                                                 const float* __restrict__ be2,
                                                 float* out_low,
                                                 float* convh)
{
    __shared__ __align__(16) unsigned short Bs[128 * 192];   // 49152 B; Cf overlays
    const int tid = threadIdx.x, lane = tid & 63;
    const int n = blockIdx.x >> 7, row = blockIdx.x & 127;

    const int wv = tid >> 6;
    const int ocw = wv >> 2, wp = (wv & 3) * 32;
    const int l15 = lane & 15, kg = lane >> 4;

    // ---- phase A: loads + bn2+mish+residual + haar (NO global stores yet)
    const int px = tid >> 2, cg = tid & 3;
    float low[16];
    v8s Hb[2], Vb[2], Db[2];
    {
        float sc[16], sh[16];
#pragma unroll
        for (int j = 0; j < 16; ++j) {
            int c = cg * 16 + j;
            float m  = g_stats[256 + 2 * c] * INV_CNT;
            float va = fmaf(g_stats[256 + 2 * c + 1], INV_CNT, -m * m);
            sc[j] = rsqrtf(va + EPS_) * g2[c];
            sh[j] = fmaf(-m, sc[j], be2[c]);
        }
        // c2 granule-v1 reads: pixel (2row+i, 2px+m), ch cg*16 + [0,16)
        const size_t cbase = (size_t)n * 2097152 + (size_t)(px >> 1) * 32768
                           + (size_t)row * 256 + (px & 1) * 128 + cg * 16;
        const size_t xbase = ((size_t)n * 65536 + (size_t)(2 * row) * 256 + 2 * px) * 64 + cg * 16;
        v8s cv[2][2][2], xv[2][2][2];
#pragma unroll
        for (int i = 0; i < 2; ++i)
#pragma unroll
            for (int m = 0; m < 2; ++m) {
                const unsigned short* cp = c2 + cbase + (size_t)i * 16777216 + m * 64;
                cv[i][m][0] = *(const v8s*)cp;
                cv[i][m][1] = *(const v8s*)(cp + 8);
                const unsigned short* xp = xh + xbase + i * 16384 + m * 64;
                xv[i][m][0] = *(const v8s*)xp;
                xv[i][m][1] = *(const v8s*)(xp + 8);
            }
#pragma unroll
        for (int jj = 0; jj < 2; ++jj)
#pragma unroll
            for (int j = 0; j < 8; ++j) {
                const int jc = jj * 8 + j;
                float y00 = mishf(fmaf(bfbits2f((unsigned short)cv[0][0][jj][j]), sc[jc], sh[jc]))
                          + bfbits2f((unsigned short)xv[0][0][jj][j]);
                float y01 = mishf(fmaf(bfbits2f((unsigned short)cv[0][1][jj][j]), sc[jc], sh[jc]))
                          + bfbits2f((unsigned short)xv[0][1][jj][j]);
                float y10 = mishf(fmaf(bfbits2f((unsigned short)cv[1][0][jj][j]), sc[jc], sh[jc]))
                          + bfbits2f((unsigned short)xv[1][0][jj][j]);
                float y11 = mishf(fmaf(bfbits2f((unsigned short)cv[1][1][jj][j]), sc[jc], sh[jc]))
                          + bfbits2f((unsigned short)xv[1][1][jj][j]);
                low[jc] = 0.5f * (y00 + y01 + y10 + y11);
                Hb[jj][j] = (short)f2bfbits(0.5f * (y00 + y01 - y10 - y11));
                Vb[jj][j] = (short)f2bfbits(0.5f * (y00 - y01 + y10 - y11));
                Db[jj][j] = (short)f2bfbits(0.5f * (y00 - y01 - y10 + y11));
            }
        unsigned short* bp = Bs + px * 192;
        const int sx = px & 7;
#pragma unroll
        for (int jj = 0; jj < 2; ++jj) {
            *(v8s*)(bp + (((cg * 2 + jj) ^ sx) << 3))      = Hb[jj];
            *(v8s*)(bp + (((8 + cg * 2 + jj) ^ sx) << 3))  = Vb[jj];
            *(v8s*)(bp + (((16 + cg * 2 + jj) ^ sx) << 3)) = Db[jj];
        }
    }
    __syncthreads();   // all c2 reads consumed block-wide; Bs ready

    // ---- out_low stores (clobber this block's own r=0 granules — now safe)
#pragma unroll
    for (int j = 0; j < 16; ++j) {
        const int c = cg * 16 + j;
        out_low[((size_t)(n * 64 + c) << 14) + row * 128 + px] = low[j];
    }

    // ---- A fragments (whT, L2-hot)
    v8s av2[6][2];
    {
        const unsigned short* wb = g_whT + (size_t)(ocw * 32 + l15) * 192 + kg * 8;
#pragma unroll
        for (int s = 0; s < 6; ++s)
#pragma unroll
            for (int sub = 0; sub < 2; ++sub)
                av2[s][sub] = *(const v8s*)(wb + (size_t)sub * 16 * 192 + s * 32);
    }

    // ---- phase B: MFMA, K=192 (6 steps)
    v4f acc[2][2];
    {
        v4f z = {0.f, 0.f, 0.f, 0.f};
        acc[0][0] = z; acc[0][1] = z; acc[1][0] = z; acc[1][1] = z;
    }
    {
        const int pix0 = wp + l15;
        const unsigned short* bbase = Bs + pix0 * 192;
        const int sx0 = pix0 & 7;
#pragma unroll
        for (int s = 0; s < 6; ++s) {
            const int ck = s * 4 + kg;
            v8s b0 = *(const v8s*)(bbase + ((ck ^ sx0) << 3));
            v8s b1 = *(const v8s*)(bbase + 16 * 192 + ((ck ^ sx0) << 3));
            acc[0][0] = __builtin_amdgcn_mfma_f32_16x16x32_bf16(av2[s][0], b0, acc[0][0], 0, 0, 0);
            acc[1][0] = __builtin_amdgcn_mfma_f32_16x16x32_bf16(av2[s][1], b0, acc[1][0], 0, 0, 0);
            acc[0][1] = __builtin_amdgcn_mfma_f32_16x16x32_bf16(av2[s][0], b1, acc[0][1], 0, 0, 0);
            acc[1][1] = __builtin_amdgcn_mfma_f32_16x16x32_bf16(av2[s][1], b1, acc[1][1], 0, 0, 0);
        }
    }

    // ---- phase C: Cf [64 oc][130 px] f32 (overlay Bs) -> coalesced NCHW + stats
    __syncthreads();
    float* Cf = (float*)Bs;
#pragma unroll
    for (int sub = 0; sub < 2; ++sub)
#pragma unroll
        for (int ps = 0; ps < 2; ++ps) {
            const int pxe = wp + ps * 16 + l15;
            const int ocb = ocw * 32 + sub * 16 + kg * 4;
#pragma unroll
            for (int r = 0; r < 4; ++r)
                Cf[(ocb + r) * 130 + pxe] = acc[sub][ps][r];
        }
    __syncthreads();
    {
        const int oc = tid >> 3, seg = tid & 7;
        float vals[16];
        float S = 0.f, Q = 0.f;
#pragma unroll
        for (int i = 0; i < 16; ++i) {
            float f = Cf[oc * 130 + seg * 16 + i];
            vals[i] = f; S += f; Q = fmaf(f, f, Q);
        }
        float* gp = convh + ((size_t)(n * 64 + oc) << 14) + row * 128 + seg * 16;
#pragma unroll
        for (int i4 = 0; i4 < 4; ++i4) {
            float4 t4;
            t4.x = vals[i4*4]; t4.y = vals[i4*4+1]; t4.z = vals[i4*4+2]; t4.w = vals[i4*4+3];
            *(float4*)(gp + i4 * 4) = t4;
        }
        S += __shfl_down(S, 4); Q += __shfl_down(Q, 4);
        S += __shfl_down(S, 2); Q += __shfl_down(Q, 2);
        S += __shfl_down(S, 1); Q += __shfl_down(Q, 1);
        if (seg == 0) {
            g_part[PBH + (size_t)blockIdx.x * 128 + 2 * oc]     = S;
            g_part[PBH + (size_t)blockIdx.x * 128 + 2 * oc + 1] = Q;
        }
    }
}

// ---------------------------------------------------------------------------
// final BN+mish on convh (NCHW f32), in place
// ---------------------------------------------------------------------------
__global__ __launch_bounds__(256) void bnF(const float* __restrict__ in,
                                           float* __restrict__ outp, int stOff,
                                           const float* __restrict__ gam,
                                           const float* __restrict__ bet,
                                           int Cmask, int logHW, float invCnt, int total4)
{
    int t = blockIdx.x * 256 + threadIdx.x;
    if (t >= total4) return;
    int idx = t << 2;
    int c = (idx >> logHW) & Cmask;
    float mean = g_stats[stOff + 2 * c] * invCnt;
    float var = fmaf(g_stats[stOff + 2 * c + 1], invCnt, -mean * mean);
    float scale = rsqrtf(var + EPS_) * gam[c];
    float shift = fmaf(-mean, scale, bet[c]);
    float4 v = *(const float4*)(in + idx);
    v.x = mishf(fmaf(v.x, scale, shift));
    v.y = mishf(fmaf(v.y, scale, shift));
    v.z = mishf(fmaf(v.z, scale, shift));
    v.w = mishf(fmaf(v.w, scale, shift));
    *(float4*)(outp + idx) = v;
}

// ---------------------------------------------------------------------------
extern "C" void kernel_launch(void* const* d_in, const int* in_sizes, int n_in,
                              void* d_out, int out_size, void* d_ws, size_t ws_size,
                              hipStream_t stream)
{
    (void)in_sizes; (void)n_in; (void)out_size; (void)ws_size;

    const float* x   = (const float*)d_in[0];
    const float* w1  = (const float*)d_in[1];
    const float* g1  = (const float*)d_in[3];
    const float* be1 = (const float*)d_in[4];
    const float* w2  = (const float*)d_in[5];
    const float* g2  = (const float*)d_in[7];
    const float* be2 = (const float*)d_in[8];
    const float* wh  = (const float*)d_in[9];
    const float* gh  = (const float*)d_in[11];
    const float* beh = (const float*)d_in[12];
    // biases b1,b2,bh are mathematically absorbed by the following BatchNorms.

    char* ws = (char*)d_ws;
    unsigned short* xh = (unsigned short*)ws;                 // x NHWC bf16 (stays live)
    unsigned short* h1 = (unsigned short*)(ws + 67108864);    // conv1 out NHWC bf16
    unsigned short* c2 = (unsigned short*)d_out;              // conv2 raw bf16, granule-v1 in d_out
    float* out_low = (float*)d_out;
    float* convh   = (float*)d_out + 8388608;

    prep<<<288, 256, 0, stream>>>(w1, w2, wh);
    transpose_x<<<8192, 256, 0, stream>>>(x, xh);

    // conv1: xh -> h1 raw (64-px tiles, 128 oc/block, 3-deep counted-vmcnt)
    conv1MFMA<<<1024, 512, 0, stream>>>(xh, h1, 8);
    // stats1: partial reduce (no atomics) + parallel final reduce
    statsP<128, PB1><<<1024, 256, 0, stream>>>(h1, 524288);
    statsR<256, PB1, 0><<<256, 256, 0, stream>>>(1024);
    bnN<128, 0><<<1024, 256, 0, stream>>>(h1, h1, g1, be1, 8388608);
    // conv2 single-pass: h1 -> c2 (granule-v1; 3-deep counted-vmcnt)
    conv2MFMA<<<2048, 512, 0, stream>>>(h1, c2, 4);
    // stats2: partial reduce + parallel final reduce
    statsP<64, PB2><<<512, 256, 0, stream>>>(c2, 524288);
    statsR<128, PB2, 256><<<128, 256, 0, stream>>>(512);
    // bn2+mish+residual(xh) + haar + 1x1 MFMA (+statsH partials)
    haarFused<<<1024, 512, 0, stream>>>(c2, xh, g2, be2, out_low, convh);
    statsR<128, PBH, 384><<<128, 256, 0, stream>>>(1024);
    // final bn+mish on convh
    bnF<<<8192, 256, 0, stream>>>(convh, convh, 384, gh, beh, 63, 14, 1.f / 131072.f, 2097152);
}